// Round 7
// baseline (838.056 us; speedup 1.0000x reference)
//
#include <hip/hip_runtime.h>
#include <hip/hip_bf16.h>
#include <stdint.h>

#define N_NODES 65536
#define N_EDGES (N_NODES * 16)
#define NEG_SLOPE 0.2f

typedef short bf16x8 __attribute__((ext_vector_type(8)));   // 8 bf16 in 4 VGPRs
typedef float f32x4 __attribute__((ext_vector_type(4)));
typedef unsigned int u32x2 __attribute__((ext_vector_type(2)));
typedef _Float16 f16x4 __attribute__((ext_vector_type(4))); // 4 fp16 = 8B

__device__ __forceinline__ unsigned short f2bf(float f) {
    unsigned u = __float_as_uint(f);
    u += 0x7fffu + ((u >> 16) & 1u);       // RNE
    return (unsigned short)(u >> 16);
}
__device__ __forceinline__ float bf2f(unsigned short h) {
    return __uint_as_float(((unsigned)h) << 16);
}
__device__ __forceinline__ unsigned short f2h(float f) {
    _Float16 h = (_Float16)f;              // v_cvt_f16_f32, RNE
    union { _Float16 h; unsigned short u; } cv; cv.h = h; return cv.u;
}
__device__ __forceinline__ float rl_f(float v, int lane) {  // wave-uniform readlane
    return __int_as_float(__builtin_amdgcn_readlane(__float_as_int(v), lane));
}
__device__ __forceinline__ void load_lds16(const void* g, void* l) {
    __builtin_amdgcn_global_load_lds(
        (const __attribute__((address_space(1))) unsigned int*)g,
        (__attribute__((address_space(3))) unsigned int*)l, 16, 0, 0);
}
// nontemporal 8B store of a ushort4 (streaming output; keep L2 for gather rows)
__device__ __forceinline__ void nt_store_us4(unsigned short* p, ushort4 v) {
    u32x2 d;
    d.x = (unsigned)v.x | ((unsigned)v.y << 16);
    d.y = (unsigned)v.z | ((unsigned)v.w << 16);
    __builtin_nontemporal_store(d, (u32x2*)p);
}

// ---------------- MFMA GEMM: C[M,Nw] = A[M,Kp] @ Wt^T ----------------
// A: fp32 (A32 path, converted during staging) or bf16 hi/lo pair.
// Wt transposed [n][Kp] bf16 hi/lo, HEAD-PADDED on N (head0 at [0,P), head1 at
// [P,2P), invalid rows zero) and K-remapped to match the padded act layout.
// Split-bf16: acc += Ahi*Bhi + Alo*Bhi + Ahi*Blo  (fp32 MFMA accumulate).
// C output: fp16 (RNE) in the padded-head layout; pads are exact zeros.
// If asrc != null: per-row attention dots al_s/al_d in FP32 (atomicAdd),
// with padded-col -> original-col remap for the a_s/a_d lookups.
template<int TN>
__global__ __launch_bounds__(256) void gemm_mfma(
    const float* __restrict__ A32, int KA,
    const unsigned short* __restrict__ Ahi, const unsigned short* __restrict__ Alo,
    int lda, int Kp,
    const unsigned short* __restrict__ Bhi, const unsigned short* __restrict__ Blo,
    unsigned short* __restrict__ C16,
    int ldc, int Nw,
    const float* __restrict__ asrc, const float* __restrict__ adst,
    float* __restrict__ alS, float* __restrict__ alD, int Cal, int Pal)
{
    constexpr int NI = TN / 32;                 // N-frags per wave
    __shared__ unsigned short sAhi[128 * 32], sAlo[128 * 32];
    __shared__ unsigned short sBhi[TN * 32],  sBlo[TN * 32];
    __shared__ float sAl[128][2][4];
    const int tid = threadIdx.x;
    const int wave = tid >> 6, lane = tid & 63;
    const int row0 = blockIdx.y * 128;
    const int col0 = blockIdx.x * TN;
    const int wm = (wave & 1) * 64, wn = (wave >> 1) * (TN / 2);
    const int mlane = lane & 15, q = lane >> 4;

    f32x4 acc[4][NI];
#pragma unroll
    for (int a = 0; a < 4; ++a)
#pragma unroll
        for (int b = 0; b < NI; ++b) acc[a][b] = (f32x4){0.f, 0.f, 0.f, 0.f};

    for (int k0 = 0; k0 < Kp; k0 += 32) {
        __syncthreads();
        if (A32) {
            // fp32 -> bf16 hi/lo conversion staging (layer 1 only)
            const int r = tid >> 1, cbase = (tid & 1) * 16;
            const float* Ap = A32 + (size_t)(row0 + r) * lda;
#pragma unroll
            for (int j = 0; j < 4; ++j) {
                int kc = k0 + cbase + j * 4;
                float4 v = make_float4(0.f, 0.f, 0.f, 0.f);
                if (kc < KA) v = *(const float4*)(Ap + kc);
                ushort4 h, l;
                h.x = f2bf(v.x); l.x = f2bf(v.x - bf2f(h.x));
                h.y = f2bf(v.y); l.y = f2bf(v.y - bf2f(h.y));
                h.z = f2bf(v.z); l.z = f2bf(v.z - bf2f(h.z));
                h.w = f2bf(v.w); l.w = f2bf(v.w - bf2f(h.w));
                *(ushort4*)(sAhi + r * 32 + cbase + j * 4) = h;
                *(ushort4*)(sAlo + r * 32 + cbase + j * 4) = l;
            }
        } else {
            // async global->LDS, 16B/lane; LDS dst = wave-uniform base + lane*16
#pragma unroll
            for (int cc = 0; cc < 2; ++cc) {
                int c = wave * 2 + cc;                 // 8 chunks of 16 rows
                int r = c * 16 + (lane >> 2);
                size_t goff = (size_t)(row0 + r) * lda + k0 + (lane & 3) * 8;
                load_lds16(Ahi + goff, sAhi + c * 512);
                load_lds16(Alo + goff, sAlo + c * 512);
            }
        }
        {
#pragma unroll
            for (int cc = 0; cc < TN / 64; ++cc) {
                int c = wave * (TN / 64) + cc;         // TN/16 chunks of 16 rows
                int r = c * 16 + (lane >> 2);
                size_t goff = (size_t)(col0 + r) * Kp + k0 + (lane & 3) * 8;
                load_lds16(Bhi + goff, sBhi + c * 512);
                load_lds16(Blo + goff, sBlo + c * 512);
            }
        }
        __syncthreads();

        bf16x8 ah[4], al[4], bh[NI], bl[NI];
#pragma unroll
        for (int mi = 0; mi < 4; ++mi) {
            int m = wm + mi * 16 + mlane;
            ah[mi] = *(const bf16x8*)(sAhi + m * 32 + q * 8);
            al[mi] = *(const bf16x8*)(sAlo + m * 32 + q * 8);
        }
#pragma unroll
        for (int ni = 0; ni < NI; ++ni) {
            int n = wn + ni * 16 + mlane;
            bh[ni] = *(const bf16x8*)(sBhi + n * 32 + q * 8);
            bl[ni] = *(const bf16x8*)(sBlo + n * 32 + q * 8);
        }
#pragma unroll
        for (int mi = 0; mi < 4; ++mi)
#pragma unroll
            for (int ni = 0; ni < NI; ++ni) {
                acc[mi][ni] = __builtin_amdgcn_mfma_f32_16x16x32_bf16(ah[mi], bh[ni], acc[mi][ni], 0, 0, 0);
                acc[mi][ni] = __builtin_amdgcn_mfma_f32_16x16x32_bf16(al[mi], bh[ni], acc[mi][ni], 0, 0, 0);
                acc[mi][ni] = __builtin_amdgcn_mfma_f32_16x16x32_bf16(ah[mi], bl[ni], acc[mi][ni], 0, 0, 0);
            }
    }

    // epilogue: C/D frag layout col=lane&15, row=(lane>>4)*4+reg; fp16 store
#pragma unroll
    for (int ni = 0; ni < NI; ++ni) {
        int col = col0 + wn + ni * 16 + mlane;
        if (col >= Nw) continue;
#pragma unroll
        for (int mi = 0; mi < 4; ++mi) {
#pragma unroll
            for (int reg = 0; reg < 4; ++reg) {
                int row = row0 + wm + mi * 16 + q * 4 + reg;
                C16[(size_t)row * ldc + col] = f2h(acc[mi][ni][reg]);
            }
        }
    }

    // fused attention-logit dots (padded-col -> orig-col remap for a_s/a_d)
    if (asrc) {
        float asv[NI], adv[NI];
        bool head0[NI];
#pragma unroll
        for (int ni = 0; ni < NI; ++ni) {
            int col = col0 + wn + ni * 16 + mlane;
            int hd = col >= Pal;
            int idc = hd ? col - Pal : col;
            bool valid = idc < Cal;
            head0[ni] = !hd;
            int borig = hd ? Cal + idc : idc;
            asv[ni] = valid ? asrc[borig] : 0.f;
            adv[ni] = valid ? adst[borig] : 0.f;
        }
#pragma unroll
        for (int mi = 0; mi < 4; ++mi) {
#pragma unroll
            for (int reg = 0; reg < 4; ++reg) {
                float s0 = 0.f, s1 = 0.f, d0 = 0.f, d1 = 0.f;
#pragma unroll
                for (int ni = 0; ni < NI; ++ni) {
                    float v = acc[mi][ni][reg];
                    if (head0[ni]) { s0 += v * asv[ni]; d0 += v * adv[ni]; }
                    else           { s1 += v * asv[ni]; d1 += v * adv[ni]; }
                }
#pragma unroll
                for (int off = 1; off < 16; off <<= 1) {
                    s0 += __shfl_xor(s0, off); s1 += __shfl_xor(s1, off);
                    d0 += __shfl_xor(d0, off); d1 += __shfl_xor(d1, off);
                }
                if (mlane == 0) {
                    int rl = wm + mi * 16 + q * 4 + reg;
                    int slot = wave >> 1;
                    sAl[rl][slot][0] = s0; sAl[rl][slot][1] = s1;
                    sAl[rl][slot][2] = d0; sAl[rl][slot][3] = d1;
                }
            }
        }
        __syncthreads();
        if (tid < 128) {
            int row = row0 + tid;
            float v0 = sAl[tid][0][0] + sAl[tid][1][0];
            float v1 = sAl[tid][0][1] + sAl[tid][1][1];
            float v2 = sAl[tid][0][2] + sAl[tid][1][2];
            float v3 = sAl[tid][0][3] + sAl[tid][1][3];
            atomicAdd(&alS[row * 2 + 0], v0);
            atomicAdd(&alS[row * 2 + 1], v1);
            atomicAdd(&alD[row * 2 + 0], v2);
            atomicAdd(&alD[row * 2 + 1], v3);
        }
    }
}

// ------------- fused MLP head: 4 layers in one kernel, 32 rows/block -------------
template<int NI>
__device__ __forceinline__ void mlp_layer(
    const unsigned short* aHi, const unsigned short* aLo, int ldaS, int K,
    const unsigned short* __restrict__ Bhi, const unsigned short* __restrict__ Blo,
    int Kp,
    unsigned short* sBh, unsigned short* sBl,
    const float* __restrict__ bias, int Nbias, int colBase,
    unsigned short* oHi, unsigned short* oLo, int ldo, int Nstore,
    float* __restrict__ gOut, int row0, int relu,
    int wave, int lane)
{
    const int mlane = lane & 15, q = lane >> 4;
    const int wm = (wave & 1) * 16;
    const int wn = (wave >> 1) * (NI * 16);
    f32x4 acc[NI];
#pragma unroll
    for (int b = 0; b < NI; ++b) acc[b] = (f32x4){0.f, 0.f, 0.f, 0.f};

    for (int k0 = 0; k0 < K; k0 += 32) {
        __syncthreads();
        for (int c = wave; c < NI * 2; c += 4) {   // stage B rows (N = NI*32)
            int r = c * 16 + (lane >> 2);
            size_t goff = (size_t)r * Kp + k0 + (lane & 3) * 8;
            load_lds16(Bhi + goff, sBh + c * 512);
            load_lds16(Blo + goff, sBl + c * 512);
        }
        __syncthreads();

        bf16x8 ah, al, bh[NI], bl[NI];
        ah = *(const bf16x8*)(aHi + (wm + mlane) * ldaS + k0 + q * 8);
        al = *(const bf16x8*)(aLo + (wm + mlane) * ldaS + k0 + q * 8);
#pragma unroll
        for (int ni = 0; ni < NI; ++ni) {
            int n = wn + ni * 16 + mlane;
            bh[ni] = *(const bf16x8*)(sBh + n * 32 + q * 8);
            bl[ni] = *(const bf16x8*)(sBl + n * 32 + q * 8);
        }
#pragma unroll
        for (int ni = 0; ni < NI; ++ni) {
            acc[ni] = __builtin_amdgcn_mfma_f32_16x16x32_bf16(ah, bh[ni], acc[ni], 0, 0, 0);
            acc[ni] = __builtin_amdgcn_mfma_f32_16x16x32_bf16(al, bh[ni], acc[ni], 0, 0, 0);
            acc[ni] = __builtin_amdgcn_mfma_f32_16x16x32_bf16(ah, bl[ni], acc[ni], 0, 0, 0);
        }
    }
    __syncthreads();   // all reads of aHi/aLo done before caller overwrites

#pragma unroll
    for (int ni = 0; ni < NI; ++ni) {
        int colg = colBase + wn + ni * 16 + mlane;
        float bv = (colg < Nbias) ? bias[colg] : 0.f;
#pragma unroll
        for (int reg = 0; reg < 4; ++reg) {
            int row = wm + q * 4 + reg;
            float v = acc[ni][reg] + bv;
            if (relu) v = fmaxf(v, 0.f);
            if (gOut) {
                if (colg < 29) gOut[(size_t)(row0 + row) * 29 + colg] = v;
            } else if (colg < Nstore) {
                unsigned short h = f2bf(v);
                oHi[row * ldo + colg] = h;
                oLo[row * ldo + colg] = f2bf(v - bf2f(h));
            }
        }
    }
}

__global__ __launch_bounds__(256) void mlp_fused(
    const unsigned short* __restrict__ actHi, const unsigned short* __restrict__ actLo,
    const unsigned short* __restrict__ L1h, const unsigned short* __restrict__ L1l,
    const unsigned short* __restrict__ L2h, const unsigned short* __restrict__ L2l,
    const unsigned short* __restrict__ L3h, const unsigned short* __restrict__ L3l,
    const unsigned short* __restrict__ L4h, const unsigned short* __restrict__ L4l,
    const float* __restrict__ B1, const float* __restrict__ B2,
    const float* __restrict__ B3, const float* __restrict__ B4,
    float* __restrict__ out)
{
    __shared__ unsigned short b1h[32 * 224], b1l[32 * 224];   // L1 out / L3 out
    __shared__ unsigned short b2h[32 * 128], b2l[32 * 128];   // L2 out
    __shared__ unsigned short sAh[32 * 32],  sAl[32 * 32];    // L1 A staging
    __shared__ unsigned short sBh[128 * 32], sBl[128 * 32];   // B staging
    const int tid = threadIdx.x;
    const int wave = tid >> 6, lane = tid & 63;
    const int row0 = blockIdx.x * 32;
    const int mlane = lane & 15, q = lane >> 4;
    const int wm = (wave & 1) * 16;
    const int wn = (wave >> 1) * 64;

    // ---- layer 1: [32,512] @ L1^T -> b1 [32,224], two 128-col tiles ----
    for (int nt = 0; nt < 2; ++nt) {
        const unsigned short* Bh = L1h + (size_t)nt * 128 * 512;
        const unsigned short* Bl = L1l + (size_t)nt * 128 * 512;
        f32x4 acc[4];
#pragma unroll
        for (int b = 0; b < 4; ++b) acc[b] = (f32x4){0.f, 0.f, 0.f, 0.f};
        for (int k0 = 0; k0 < 512; k0 += 32) {
            __syncthreads();
            for (int c = wave; c < 2; c += 4) {      // A: 32 rows
                int r = c * 16 + (lane >> 2);
                size_t goff = (size_t)(row0 + r) * 512 + k0 + (lane & 3) * 8;
                load_lds16(actHi + goff, sAh + c * 512);
                load_lds16(actLo + goff, sAl + c * 512);
            }
            for (int c = wave; c < 8; c += 4) {      // B: 128 rows
                int r = c * 16 + (lane >> 2);
                size_t goff = (size_t)r * 512 + k0 + (lane & 3) * 8;
                load_lds16(Bh + goff, sBh + c * 512);
                load_lds16(Bl + goff, sBl + c * 512);
            }
            __syncthreads();
            bf16x8 ah = *(const bf16x8*)(sAh + (wm + mlane) * 32 + q * 8);
            bf16x8 al = *(const bf16x8*)(sAl + (wm + mlane) * 32 + q * 8);
#pragma unroll
            for (int ni = 0; ni < 4; ++ni) {
                int n = wn + ni * 16 + mlane;
                bf16x8 bh = *(const bf16x8*)(sBh + n * 32 + q * 8);
                bf16x8 bl = *(const bf16x8*)(sBl + n * 32 + q * 8);
                acc[ni] = __builtin_amdgcn_mfma_f32_16x16x32_bf16(ah, bh, acc[ni], 0, 0, 0);
                acc[ni] = __builtin_amdgcn_mfma_f32_16x16x32_bf16(al, bh, acc[ni], 0, 0, 0);
                acc[ni] = __builtin_amdgcn_mfma_f32_16x16x32_bf16(ah, bl, acc[ni], 0, 0, 0);
            }
        }
        __syncthreads();
#pragma unroll
        for (int ni = 0; ni < 4; ++ni) {
            int colg = nt * 128 + wn + ni * 16 + mlane;
            float bv = (colg < 200) ? B1[colg] : 0.f;
#pragma unroll
            for (int reg = 0; reg < 4; ++reg) {
                int row = wm + q * 4 + reg;
                float v = fmaxf(acc[ni][reg] + bv, 0.f);
                if (colg < 224) {
                    unsigned short h = f2bf(v);
                    b1h[row * 224 + colg] = h;
                    b1l[row * 224 + colg] = f2bf(v - bf2f(h));
                }
            }
        }
    }
    __syncthreads();

    // ---- layer 2: b1[32,224] -> b2[32,128] ----
    mlp_layer<4>(b1h, b1l, 224, 224, L2h, L2l, 224, sBh, sBl,
                 B2, 100, 0, b2h, b2l, 128, 128, nullptr, 0, 1, wave, lane);
    __syncthreads();
    // ---- layer 3: b2[32,128] -> b1[32,128] (reuse, ld 128) ----
    mlp_layer<4>(b2h, b2l, 128, 128, L3h, L3l, 128, sBh, sBl,
                 B3, 100, 0, b1h, b1l, 128, 128, nullptr, 0, 1, wave, lane);
    __syncthreads();
    // ---- layer 4: b1[32,128] -> out[32,29] fp32 ----
    mlp_layer<2>(b1h, b1l, 128, 128, L4h, L4l, 128, sBh, sBl,
                 B4, 29, 0, nullptr, nullptr, 0, 0, out, row0, 0, wave, lane);
}

// ------- weight transpose + bf16 hi/lo decompose (all 8 in one) -------
// N-remap (Pn>0): output rows laid out head-padded [head0 | pad | head1 | pad];
// invalid rows -> zero weights (GEMM then writes exact 0 at pad cols).
// K-remap (Pk>0): input features read from the head-padded act layout
// (per kblk-block: [0,Pk) head0, [Pk,2Pk) head1, rest invalid -> zero rows,
// making act pad values mathematically inert).
struct WtJob {
    const float* W; unsigned short* Whi; unsigned short* Wlo;
    int N, Kp, K, nb0, Cn, Pn, Ck, Pk, kblk;
};
struct WtJobs { WtJob j[8]; };

__global__ void wt_decomp_all(WtJobs jobs)
{
    int b = blockIdx.x;
    int idx = 0;
#pragma unroll
    for (int i = 1; i < 8; ++i)
        if (b >= jobs.j[i].nb0) idx = i;
    WtJob jb = jobs.j[idx];
    int n = b - jb.nb0;
    int norig = n; bool nvalid;
    if (jb.Pn) {
        int hn = n >= jb.Pn;
        int r = hn ? n - jb.Pn : n;
        nvalid = r < jb.Cn;
        norig = hn ? jb.Cn + r : r;
    } else {
        nvalid = n < jb.N;
    }
    for (int k = threadIdx.x; k < jb.Kp; k += 256) {
        int ks; bool kvalid;
        if (jb.Pk) {
            int node = k / jb.kblk;
            int r = k - node * jb.kblk;
            int rr, off;
            if (r < jb.Pk) { rr = r; off = 0; kvalid = rr < jb.Ck; }
            else if (r < 2 * jb.Pk) { rr = r - jb.Pk; off = jb.Ck; kvalid = rr < jb.Ck; }
            else { rr = 0; off = 0; kvalid = false; }
            ks = node * (2 * jb.Ck) + off + rr;
        } else {
            ks = k; kvalid = k < jb.K;
        }
        float v = 0.f;
        if (nvalid && kvalid) v = jb.W[(size_t)ks * jb.N + norig];
        unsigned short h = f2bf(v);
        jb.Whi[(size_t)n * jb.Kp + k] = h;
        jb.Wlo[(size_t)n * jb.Kp + k] = f2bf(v - bf2f(h));
    }
}

// ------- fused stats+gather (all 4 layers, one wave per node) -------
// Head-padded column layout: head boundary at P (multiple of 4) -> per-lane
// head flag hd1 is uniform over the lane's 4 cols -> ONE weight select per
// edge, and pad h-values are exact zeros so no per-element C-masks.
// deg<=64 fast path: chunk-0 lanes own one edge each; e computed once; max
// butterfly; den = butterfly-sum of exp(e-m) (numerator doubles as weight).
// G==1: wave-uniform readlane broadcast + scalar row address; unroll x4 with
// zero-weight padding (extra iters hit row 0, harmless).
template<int LPE>
__global__ __launch_bounds__(256) void gat_gather_fused(
    const unsigned short* __restrict__ h16,
    const float* __restrict__ al_s, const float* __restrict__ al_d,
    const int* __restrict__ indptr, const unsigned short* __restrict__ csr_src,
    const float* __restrict__ bias,
    unsigned short* __restrict__ outHi, unsigned short* __restrict__ outLo,
    int ldo, int Nn, int C, int P, int HCpad)
{
    constexpr int G = 64 / LPE;
    const int wave = threadIdx.x >> 6, lane = threadIdx.x & 63;
    const int i = blockIdx.x * 4 + wave;
    if (i >= Nn) return;
    const int start = indptr[i], end = indptr[i + 1];
    const int deg = end - start;
    const float ad0 = al_d[2 * i], ad1 = al_d[2 * i + 1];

    const int l = lane % LPE;
    const int g = lane / LPE;
    const int ch4 = l * 4;
    const bool chA = ch4 < HCpad;
    const bool hd1 = ch4 >= P;          // uniform over the lane's 4 cols
    float a0 = 0.f, a1 = 0.f, a2 = 0.f, a3 = 0.f;

    if (deg <= 64) {
        // ---------------- fast path ----------------
        const int jW = start + lane;
        const bool have = jW < end;
        int ps = 0;
        float e0r = 0.f, e1r = 0.f;
        if (have) {
            ps = csr_src[jW];
            float2 as = *(const float2*)(al_s + 2 * ps);
            e0r = as.x + ad0; e0r = e0r > 0.f ? e0r : NEG_SLOPE * e0r;
            e1r = as.y + ad1; e1r = e1r > 0.f ? e1r : NEG_SLOPE * e1r;
        }
        float m0 = have ? e0r : -1e30f;
        float m1 = have ? e1r : -1e30f;
#pragma unroll
        for (int off = 32; off; off >>= 1) {
            m0 = fmaxf(m0, __shfl_xor(m0, off));
            m1 = fmaxf(m1, __shfl_xor(m1, off));
        }
        float n0 = have ? __expf(e0r - m0) : 0.f;
        float n1 = have ? __expf(e1r - m1) : 0.f;
        float den0 = n0, den1 = n1;
#pragma unroll
        for (int off = 32; off; off >>= 1) {
            den0 += __shfl_xor(den0, off);
            den1 += __shfl_xor(den1, off);
        }
        const float pw0 = n0 * (1.f / den0);
        const float pw1 = n1 * (1.f / den1);

        if constexpr (G == 1) {
            const int dr = (deg + 3) & ~3;     // pad iters: pw=0, row 0
#pragma unroll 4
            for (int u = 0; u < dr; ++u) {
                float w0 = rl_f(pw0, u);
                float w1 = rl_f(pw1, u);
                float w = hd1 ? w1 : w0;
                int s = __builtin_amdgcn_readlane(ps, u);
                float hx = 0.f, hy = 0.f, hz = 0.f, hw = 0.f;
                if (chA) {
                    f16x4 hv = *(const f16x4*)(h16 + (size_t)s * HCpad + ch4);
                    hx = (float)hv[0]; hy = (float)hv[1];
                    hz = (float)hv[2]; hw = (float)hv[3];
                }
                a0 = fmaf(w, hx, a0);
                a1 = fmaf(w, hy, a1);
                a2 = fmaf(w, hz, a2);
                a3 = fmaf(w, hw, a3);
            }
        } else {
            const int nit = (deg + G - 1) / G;
            const int nit4 = (nit + 3) & ~3;   // idx stays < 64 (see bounds)
#pragma unroll 4
            for (int u = 0; u < nit4; ++u) {
                int idx = u * G + g;
                float w0 = __shfl(pw0, idx);
                float w1 = __shfl(pw1, idx);
                float w = hd1 ? w1 : w0;
                int s = __shfl(ps, idx);
                float hx = 0.f, hy = 0.f, hz = 0.f, hw = 0.f;
                if (chA) {
                    f16x4 hv = *(const f16x4*)(h16 + (size_t)s * HCpad + ch4);
                    hx = (float)hv[0]; hy = (float)hv[1];
                    hz = (float)hv[2]; hw = (float)hv[3];
                }
                a0 = fmaf(w, hx, a0);
                a1 = fmaf(w, hy, a1);
                a2 = fmaf(w, hz, a2);
                a3 = fmaf(w, hw, a3);
            }
        }
    } else {
        // ---------------- fallback: online-stats path (rare) ----------------
        float m0 = -1e30f, m1 = -1e30f, den0 = 0.f, den1 = 0.f;
        for (int j = start + lane; j < end; j += 64) {
            int s = csr_src[j];
            float2 as = *(const float2*)(al_s + 2 * s);
            float e0 = as.x + ad0; e0 = e0 > 0.f ? e0 : NEG_SLOPE * e0;
            float e1 = as.y + ad1; e1 = e1 > 0.f ? e1 : NEG_SLOPE * e1;
            float n0 = fmaxf(m0, e0);
            den0 = den0 * __expf(m0 - n0) + __expf(e0 - n0);
            m0 = n0;
            float n1 = fmaxf(m1, e1);
            den1 = den1 * __expf(m1 - n1) + __expf(e1 - n1);
            m1 = n1;
        }
#pragma unroll
        for (int off = 32; off; off >>= 1) {
            float mo0 = __shfl_xor(m0, off), do0 = __shfl_xor(den0, off);
            float n0 = fmaxf(m0, mo0);
            den0 = den0 * __expf(m0 - n0) + do0 * __expf(mo0 - n0);
            m0 = n0;
            float mo1 = __shfl_xor(m1, off), do1 = __shfl_xor(den1, off);
            float n1 = fmaxf(m1, mo1);
            den1 = den1 * __expf(m1 - n1) + do1 * __expf(mo1 - n1);
            m1 = n1;
        }
        const float inv0 = 1.f / den0, inv1 = 1.f / den1;

        for (int jb = start; jb < end; jb += 64) {
            int jW = jb + lane;
            float pw0 = 0.f, pw1 = 0.f;
            int ps = 0;
            if (jW < end) {
                ps = csr_src[jW];
                float2 as = *(const float2*)(al_s + 2 * ps);
                float e0 = as.x + ad0; e0 = e0 > 0.f ? e0 : NEG_SLOPE * e0;
                float e1 = as.y + ad1; e1 = e1 > 0.f ? e1 : NEG_SLOPE * e1;
                pw0 = __expf(e0 - m0) * inv0;
                pw1 = __expf(e1 - m1) * inv1;
            }
            int nedge = end - jb; if (nedge > 64) nedge = 64;
            int nit = (nedge + G - 1) / G;
            for (int u = 0; u < nit; ++u) {
                int idx = u * G + g;
                float w0 = __shfl(pw0, idx);
                float w1 = __shfl(pw1, idx);
                float w = hd1 ? w1 : w0;
                int s = __shfl(ps, idx);
                float hx = 0.f, hy = 0.f, hz = 0.f, hw = 0.f;
                if (chA) {
                    f16x4 hv = *(const f16x4*)(h16 + (size_t)s * HCpad + ch4);
                    hx = (float)hv[0]; hy = (float)hv[1];
                    hz = (float)hv[2]; hw = (float)hv[3];
                }
                a0 = fmaf(w, hx, a0);
                a1 = fmaf(w, hy, a1);
                a2 = fmaf(w, hz, a2);
                a3 = fmaf(w, hw, a3);
            }
        }
    }

    // ---- shared tail: cross-group reduce, bias+relu (orig-col remap), store ----
#pragma unroll
    for (int off = LPE; off < 64; off <<= 1) {
        a0 += __shfl_xor(a0, off);
        a1 += __shfl_xor(a1, off);
        a2 += __shfl_xor(a2, off);
        a3 += __shfl_xor(a3, off);
    }
    if (g == 0 && chA) {
        float av[4] = {a0, a1, a2, a3};
        unsigned short hi4[4], lo4[4];
#pragma unroll
        for (int k = 0; k < 4; ++k) {
            int colp = ch4 + k;
            int idc = hd1 ? colp - P : colp;
            bool vld = idc < C;
            float bv = vld ? bias[hd1 ? C + idc : idc] : 0.f;
            float v = vld ? fmaxf(av[k] + bv, 0.f) : 0.f;   // pads -> exact 0
            unsigned short h = f2bf(v);
            hi4[k] = h;
            lo4[k] = f2bf(v - bf2f(h));
        }
        ushort4 h = {hi4[0], hi4[1], hi4[2], hi4[3]};
        ushort4 lo = {lo4[0], lo4[1], lo4[2], lo4[3]};
        nt_store_us4(outHi + (size_t)i * ldo + ch4, h);
        nt_store_us4(outLo + (size_t)i * ldo + ch4, lo);
    }
    for (int z = HCpad + lane * 4; z < ldo; z += 256) {
        ushort4 zz; zz.x = zz.y = zz.z = zz.w = 0;
        *(ushort4*)(outHi + (size_t)i * ldo + z) = zz;
        *(ushort4*)(outLo + (size_t)i * ldo + z) = zz;
    }
}

// ---------------- CSR build (with self-loops folded in) ----------------
__global__ void hist_self_k(const int* __restrict__ dst, int E,
                            int* __restrict__ counts, int n)
{
    int gid = blockIdx.x * blockDim.x + threadIdx.x;
    if (gid < E) atomicAdd(&counts[dst[gid]], 1);
    else if (gid < E + n) atomicAdd(&counts[gid - E], 1);
}

__global__ void scan_block_k(const int* __restrict__ in, int* __restrict__ out,
                             int* __restrict__ bsum, int n)
{
    __shared__ int sh[256];
    int gid = blockIdx.x * 256 + threadIdx.x;
    int v = (gid < n) ? in[gid] : 0;
    sh[threadIdx.x] = v;
    __syncthreads();
    for (int off = 1; off < 256; off <<= 1) {
        int t = (threadIdx.x >= off) ? sh[threadIdx.x - off] : 0;
        __syncthreads();
        sh[threadIdx.x] += t;
        __syncthreads();
    }
    int incl = sh[threadIdx.x];
    if (gid < n) out[gid] = incl - v;
    if (threadIdx.x == 255) bsum[blockIdx.x] = incl;
}

__global__ void scan_tops_k(const int* __restrict__ bsum, int* __restrict__ boff)
{
    __shared__ int sh[256];
    int v = bsum[threadIdx.x];
    sh[threadIdx.x] = v;
    __syncthreads();
    for (int off = 1; off < 256; off <<= 1) {
        int t = (threadIdx.x >= off) ? sh[threadIdx.x - off] : 0;
        __syncthreads();
        sh[threadIdx.x] += t;
        __syncthreads();
    }
    boff[threadIdx.x] = sh[threadIdx.x] - v;
}

__global__ void scan_add_k(int* __restrict__ indptr, const int* __restrict__ boff,
                           int n, int Etot)
{
    int gid = blockIdx.x * 256 + threadIdx.x;
    if (gid < n) indptr[gid] += boff[blockIdx.x];
    if (gid == 0) indptr[n] = Etot;
}

__global__ void fill_all_k(const int* __restrict__ src, const int* __restrict__ dst,
                           int E, const int* __restrict__ indptr,
                           int* __restrict__ cursor,
                           unsigned short* __restrict__ csr_src, int n)
{
    int gid = blockIdx.x * blockDim.x + threadIdx.x;
    if (gid < E) {
        int d = dst[gid];
        int pos = atomicAdd(&cursor[d], 1);
        csr_src[indptr[d] + pos] = (unsigned short)src[gid];
    } else if (gid < E + n) {
        int i = gid - E;
        int pos = atomicAdd(&cursor[i], 1);
        csr_src[indptr[i] + pos] = (unsigned short)i;
    }
}

// ---------------- launch ----------------
extern "C" void kernel_launch(void* const* d_in, const int* in_sizes, int n_in,
                              void* d_out, int out_size, void* d_ws, size_t ws_size,
                              hipStream_t stream)
{
    (void)in_sizes; (void)n_in; (void)out_size; (void)ws_size;
    const int N = N_NODES;
    const int E = N_EDGES;
    const int Etot = E + N;

    const float* x = (const float*)d_in[0];
    const int* ei = (const int*)d_in[1];
    const float* Wc[4] = {(const float*)d_in[3], (const float*)d_in[7],
                          (const float*)d_in[11], (const float*)d_in[15]};
    const float* AS[4] = {(const float*)d_in[4], (const float*)d_in[8],
                          (const float*)d_in[12], (const float*)d_in[16]};
    const float* AD[4] = {(const float*)d_in[5], (const float*)d_in[9],
                          (const float*)d_in[13], (const float*)d_in[17]};
    const float* Bc[4] = {(const float*)d_in[6], (const float*)d_in[10],
                          (const float*)d_in[14], (const float*)d_in[18]};
    const float* LW[4] = {(const float*)d_in[19], (const float*)d_in[21],
                          (const float*)d_in[23], (const float*)d_in[25]};
    const float* LB[4] = {(const float*)d_in[20], (const float*)d_in[22],
                          (const float*)d_in[24], (const float*)d_in[26]};

    char* w = (char*)d_ws;
    auto alloc = [&](size_t bytes) -> char* {
        char* p = w; w += (bytes + 255) & ~(size_t)255; return p;
    };
    unsigned short* bufC16 = (unsigned short*)alloc((size_t)N * 256 * 2); // GEMM out, fp16
    unsigned short* actHi = (unsigned short*)alloc((size_t)N * 256 * 2);
    unsigned short* actLo = (unsigned short*)alloc((size_t)N * 256 * 2);
    unsigned short* csr = (unsigned short*)alloc((size_t)Etot * 2);  // u16 src ids
    // alSD (4 layers x [alS|alD]) + counts/cursor: contiguous, single memset
    float* alSD = (float*)alloc((size_t)N * 4 * 4 * 4 + (size_t)N * 2 * 4);
    int* cnt2   = (int*)(alSD + (size_t)N * 16);
    int* counts = cnt2;
    int* cursor = cnt2 + N;
    int* indptr = (int*)alloc((size_t)(N + 8) * 4);
    int* bsum   = (int*)alloc(1024);
    int* boff   = (int*)alloc(1024);

    const int KpConv[4] = {352, 256, 160, 128};
    const int NpConv[4] = {256, 192, 128, 64};
    const int KpLin[4]  = {512, 224, 128, 128};
    const int NpLin[4]  = {256, 128, 128, 64};
    unsigned short *WtHi[4], *WtLo[4], *LtHi[4], *LtLo[4];
    for (int l = 0; l < 4; ++l) {
        WtHi[l] = (unsigned short*)alloc((size_t)NpConv[l] * KpConv[l] * 2);
        WtLo[l] = (unsigned short*)alloc((size_t)NpConv[l] * KpConv[l] * 2);
    }
    for (int l = 0; l < 4; ++l) {
        LtHi[l] = (unsigned short*)alloc((size_t)NpLin[l] * KpLin[l] * 2);
        LtLo[l] = (unsigned short*)alloc((size_t)NpLin[l] * KpLin[l] * 2);
    }

    const int* esrc = ei;
    const int* edst = ei + E;

    // ---- CSR by dst incl. self-loops; zero al buffers + counts in one memset ----
    hipMemsetAsync(alSD, 0, (size_t)N * 4 * 4 * 4 + (size_t)N * 2 * 4, stream);
    hist_self_k<<<(E + N) / 256, 256, 0, stream>>>(edst, E, counts, N);
    scan_block_k<<<N / 256, 256, 0, stream>>>(counts, indptr, bsum, N);
    scan_tops_k<<<1, 256, 0, stream>>>(bsum, boff);
    scan_add_k<<<N / 256, 256, 0, stream>>>(indptr, boff, N, Etot);
    fill_all_k<<<(E + N) / 256, 256, 0, stream>>>(esrc, edst, E, indptr, cursor, csr, N);

    // ---- weight decompose: head-padded N-remap + act-layout K-remap ----
    const int Cc[4] = {125, 75, 50, 30};       // per-head cols
    const int Pc[4] = {128, 76, 52, 32};       // head pad (align 4)
    const int Nc[4] = {250, 150, 100, 60};
    const int Kl[4] = {480, 200, 100, 100};
    const int Nl[4] = {200, 100, 100, 29};
    WtJobs jobs;
    int nb = 0;
    for (int l = 0; l < 4; ++l) {
        WtJob jb;
        jb.W = Wc[l]; jb.Whi = WtHi[l]; jb.Wlo = WtLo[l];
        jb.N = Nc[l]; jb.Kp = KpConv[l]; jb.nb0 = nb;
        jb.Cn = Cc[l]; jb.Pn = Pc[l];
        if (l == 0) { jb.Pk = 0; jb.Ck = 0; jb.kblk = 1; jb.K = 336; }
        else { jb.Pk = Pc[l-1]; jb.Ck = Cc[l-1]; jb.kblk = KpConv[l]; jb.K = 0; }
        jobs.j[l] = jb;
        nb += NpConv[l];
    }
    for (int l = 0; l < 4; ++l) {
        WtJob jb;
        jb.W = LW[l]; jb.Whi = LtHi[l]; jb.Wlo = LtLo[l];
        jb.N = Nl[l]; jb.Kp = KpLin[l]; jb.nb0 = nb;
        jb.Cn = 0; jb.Pn = 0;
        if (l == 0) { jb.Pk = Pc[3]; jb.Ck = Cc[3]; jb.kblk = 64; jb.K = 0; }
        else { jb.Pk = 0; jb.Ck = 0; jb.kblk = 1; jb.K = Kl[l]; }
        jobs.j[4 + l] = jb;
        nb += NpLin[l];
    }
    wt_decomp_all<<<nb, 256, 0, stream>>>(jobs);

    // ---- 4 GAT layers (head-padded fp16 h; stats fused into every gather) ----
    const int HCp[4]  = {256, 152, 104, 64};   // bufC16 stride = 2P
    const int ldoA[4] = {256, 160, 128, 64};   // act stride (= next Kp)
    const int ldaA[4] = {336, 256, 160, 128};  // A leading dim into GEMM
    for (int l = 0; l < 4; ++l) {
        float* alS = alSD + (size_t)l * N * 4;
        float* alD = alS + (size_t)N * 2;
        if (l == 0) {
            gemm_mfma<128><<<dim3(2, N / 128), 256, 0, stream>>>(
                x, 336, nullptr, nullptr, 336, 352,
                WtHi[0], WtLo[0],
                bufC16, HCp[0], HCp[0],
                AS[0], AD[0], alS, alD, Cc[0], Pc[0]);
        } else if (l == 1) {
            gemm_mfma<64><<<dim3(3, N / 128), 256, 0, stream>>>(
                nullptr, 0, actHi, actLo, ldaA[1], KpConv[1],
                WtHi[1], WtLo[1],
                bufC16, HCp[1], HCp[1],
                AS[1], AD[1], alS, alD, Cc[1], Pc[1]);
        } else if (l == 2) {
            gemm_mfma<128><<<dim3(1, N / 128), 256, 0, stream>>>(
                nullptr, 0, actHi, actLo, ldaA[2], KpConv[2],
                WtHi[2], WtLo[2],
                bufC16, HCp[2], HCp[2],
                AS[2], AD[2], alS, alD, Cc[2], Pc[2]);
        } else {
            gemm_mfma<64><<<dim3(1, N / 128), 256, 0, stream>>>(
                nullptr, 0, actHi, actLo, ldaA[3], KpConv[3],
                WtHi[3], WtLo[3],
                bufC16, HCp[3], HCp[3],
                AS[3], AD[3], alS, alD, Cc[3], Pc[3]);
        }
        if (l == 0) {
            gat_gather_fused<64><<<N / 4, 256, 0, stream>>>(
                bufC16, alS, alD, indptr, csr, Bc[0],
                actHi, actLo, ldoA[0], N, Cc[0], Pc[0], HCp[0]);
        } else if (l == 1) {
            gat_gather_fused<64><<<N / 4, 256, 0, stream>>>(
                bufC16, alS, alD, indptr, csr, Bc[1],
                actHi, actLo, ldoA[1], N, Cc[1], Pc[1], HCp[1]);
        } else if (l == 2) {
            gat_gather_fused<32><<<N / 4, 256, 0, stream>>>(
                bufC16, alS, alD, indptr, csr, Bc[2],
                actHi, actLo, ldoA[2], N, Cc[2], Pc[2], HCp[2]);
        } else {
            gat_gather_fused<16><<<N / 4, 256, 0, stream>>>(
                bufC16, alS, alD, indptr, csr, Bc[3],
                actHi, actLo, ldoA[3], N, Cc[3], Pc[3], HCp[3]);
        }
    }

    // ---- MLP head, fused: [8192,480(512 head-padded)] -> 200 -> 100 -> 100 -> 29 ----
    mlp_fused<<<8192 / 32, 256, 0, stream>>>(
        actHi, actLo,
        LtHi[0], LtLo[0], LtHi[1], LtLo[1],
        LtHi[2], LtLo[2], LtHi[3], LtLo[3],
        LB[0], LB[1], LB[2], LB[3],
        (float*)d_out);
}

// Round 9
// 824.954 us; speedup vs baseline: 1.0159x; 1.0159x over previous
//
#include <hip/hip_runtime.h>
#include <hip/hip_bf16.h>
#include <stdint.h>

#define N_NODES 65536
#define N_EDGES (N_NODES * 16)
#define NEG_SLOPE 0.2f

typedef short bf16x8 __attribute__((ext_vector_type(8)));   // 8 bf16 in 4 VGPRs
typedef float f32x4 __attribute__((ext_vector_type(4)));
typedef unsigned int u32x2 __attribute__((ext_vector_type(2)));
typedef _Float16 f16x4 __attribute__((ext_vector_type(4))); // 4 fp16 = 8B

__device__ __forceinline__ unsigned short f2bf(float f) {
    unsigned u = __float_as_uint(f);
    u += 0x7fffu + ((u >> 16) & 1u);       // RNE
    return (unsigned short)(u >> 16);
}
__device__ __forceinline__ float bf2f(unsigned short h) {
    return __uint_as_float(((unsigned)h) << 16);
}
__device__ __forceinline__ unsigned short f2h(float f) {
    _Float16 h = (_Float16)f;              // v_cvt_f16_f32, RNE
    union { _Float16 h; unsigned short u; } cv; cv.h = h; return cv.u;
}
__device__ __forceinline__ float rl_f(float v, int lane) {  // wave-uniform readlane
    return __int_as_float(__builtin_amdgcn_readlane(__float_as_int(v), lane));
}
__device__ __forceinline__ void load_lds16(const void* g, void* l) {
    __builtin_amdgcn_global_load_lds(
        (const __attribute__((address_space(1))) unsigned int*)g,
        (__attribute__((address_space(3))) unsigned int*)l, 16, 0, 0);
}
// nontemporal 8B store of a ushort4 (streaming output; keep L2 for gather rows)
__device__ __forceinline__ void nt_store_us4(unsigned short* p, ushort4 v) {
    u32x2 d;
    d.x = (unsigned)v.x | ((unsigned)v.y << 16);
    d.y = (unsigned)v.z | ((unsigned)v.w << 16);
    __builtin_nontemporal_store(d, (u32x2*)p);
}

// ---------------- MFMA GEMM: C[M,Nw] = A[M,Kp] @ Wt^T ----------------
// A: fp32 (A32 path, converted during staging) or bf16 hi/lo pair.
// Wt transposed [n][Kp] bf16 hi/lo, HEAD-PADDED on N (head0 at [0,P), head1 at
// [P,2P), invalid rows zero) and K-remapped to match the padded act layout.
// Split-bf16: acc += Ahi*Bhi + Alo*Bhi + Ahi*Blo  (fp32 MFMA accumulate).
// C output: fp16 (RNE) in the padded-head layout; pads are exact zeros.
// If asrc != null: per-row attention dots al_s/al_d in FP32 (atomicAdd),
// with padded-col -> original-col remap for the a_s/a_d lookups.
template<int TN>
__global__ __launch_bounds__(256) void gemm_mfma(
    const float* __restrict__ A32, int KA,
    const unsigned short* __restrict__ Ahi, const unsigned short* __restrict__ Alo,
    int lda, int Kp,
    const unsigned short* __restrict__ Bhi, const unsigned short* __restrict__ Blo,
    unsigned short* __restrict__ C16,
    int ldc, int Nw,
    const float* __restrict__ asrc, const float* __restrict__ adst,
    float* __restrict__ alS, float* __restrict__ alD, int Cal, int Pal)
{
    constexpr int NI = TN / 32;                 // N-frags per wave
    __shared__ unsigned short sAhi[128 * 32], sAlo[128 * 32];
    __shared__ unsigned short sBhi[TN * 32],  sBlo[TN * 32];
    __shared__ float sAl[128][2][4];
    const int tid = threadIdx.x;
    const int wave = tid >> 6, lane = tid & 63;
    const int row0 = blockIdx.y * 128;
    const int col0 = blockIdx.x * TN;
    const int wm = (wave & 1) * 64, wn = (wave >> 1) * (TN / 2);
    const int mlane = lane & 15, q = lane >> 4;

    f32x4 acc[4][NI];
#pragma unroll
    for (int a = 0; a < 4; ++a)
#pragma unroll
        for (int b = 0; b < NI; ++b) acc[a][b] = (f32x4){0.f, 0.f, 0.f, 0.f};

    for (int k0 = 0; k0 < Kp; k0 += 32) {
        __syncthreads();
        if (A32) {
            // fp32 -> bf16 hi/lo conversion staging (layer 1 only)
            const int r = tid >> 1, cbase = (tid & 1) * 16;
            const float* Ap = A32 + (size_t)(row0 + r) * lda;
#pragma unroll
            for (int j = 0; j < 4; ++j) {
                int kc = k0 + cbase + j * 4;
                float4 v = make_float4(0.f, 0.f, 0.f, 0.f);
                if (kc < KA) v = *(const float4*)(Ap + kc);
                ushort4 h, l;
                h.x = f2bf(v.x); l.x = f2bf(v.x - bf2f(h.x));
                h.y = f2bf(v.y); l.y = f2bf(v.y - bf2f(h.y));
                h.z = f2bf(v.z); l.z = f2bf(v.z - bf2f(h.z));
                h.w = f2bf(v.w); l.w = f2bf(v.w - bf2f(h.w));
                *(ushort4*)(sAhi + r * 32 + cbase + j * 4) = h;
                *(ushort4*)(sAlo + r * 32 + cbase + j * 4) = l;
            }
        } else {
            // async global->LDS, 16B/lane; LDS dst = wave-uniform base + lane*16
#pragma unroll
            for (int cc = 0; cc < 2; ++cc) {
                int c = wave * 2 + cc;                 // 8 chunks of 16 rows
                int r = c * 16 + (lane >> 2);
                size_t goff = (size_t)(row0 + r) * lda + k0 + (lane & 3) * 8;
                load_lds16(Ahi + goff, sAhi + c * 512);
                load_lds16(Alo + goff, sAlo + c * 512);
            }
        }
        {
#pragma unroll
            for (int cc = 0; cc < TN / 64; ++cc) {
                int c = wave * (TN / 64) + cc;         // TN/16 chunks of 16 rows
                int r = c * 16 + (lane >> 2);
                size_t goff = (size_t)(col0 + r) * Kp + k0 + (lane & 3) * 8;
                load_lds16(Bhi + goff, sBhi + c * 512);
                load_lds16(Blo + goff, sBlo + c * 512);
            }
        }
        __syncthreads();

        bf16x8 ah[4], al[4], bh[NI], bl[NI];
#pragma unroll
        for (int mi = 0; mi < 4; ++mi) {
            int m = wm + mi * 16 + mlane;
            ah[mi] = *(const bf16x8*)(sAhi + m * 32 + q * 8);
            al[mi] = *(const bf16x8*)(sAlo + m * 32 + q * 8);
        }
#pragma unroll
        for (int ni = 0; ni < NI; ++ni) {
            int n = wn + ni * 16 + mlane;
            bh[ni] = *(const bf16x8*)(sBhi + n * 32 + q * 8);
            bl[ni] = *(const bf16x8*)(sBlo + n * 32 + q * 8);
        }
#pragma unroll
        for (int mi = 0; mi < 4; ++mi)
#pragma unroll
            for (int ni = 0; ni < NI; ++ni) {
                acc[mi][ni] = __builtin_amdgcn_mfma_f32_16x16x32_bf16(ah[mi], bh[ni], acc[mi][ni], 0, 0, 0);
                acc[mi][ni] = __builtin_amdgcn_mfma_f32_16x16x32_bf16(al[mi], bh[ni], acc[mi][ni], 0, 0, 0);
                acc[mi][ni] = __builtin_amdgcn_mfma_f32_16x16x32_bf16(ah[mi], bl[ni], acc[mi][ni], 0, 0, 0);
            }
    }

    // epilogue: C/D frag layout col=lane&15, row=(lane>>4)*4+reg; fp16 store
#pragma unroll
    for (int ni = 0; ni < NI; ++ni) {
        int col = col0 + wn + ni * 16 + mlane;
        if (col >= Nw) continue;
#pragma unroll
        for (int mi = 0; mi < 4; ++mi) {
#pragma unroll
            for (int reg = 0; reg < 4; ++reg) {
                int row = row0 + wm + mi * 16 + q * 4 + reg;
                C16[(size_t)row * ldc + col] = f2h(acc[mi][ni][reg]);
            }
        }
    }

    // fused attention-logit dots (padded-col -> orig-col remap for a_s/a_d)
    if (asrc) {
        float asv[NI], adv[NI];
        bool head0[NI];
#pragma unroll
        for (int ni = 0; ni < NI; ++ni) {
            int col = col0 + wn + ni * 16 + mlane;
            int hd = col >= Pal;
            int idc = hd ? col - Pal : col;
            bool valid = idc < Cal;
            head0[ni] = !hd;
            int borig = hd ? Cal + idc : idc;
            asv[ni] = valid ? asrc[borig] : 0.f;
            adv[ni] = valid ? adst[borig] : 0.f;
        }
#pragma unroll
        for (int mi = 0; mi < 4; ++mi) {
#pragma unroll
            for (int reg = 0; reg < 4; ++reg) {
                float s0 = 0.f, s1 = 0.f, d0 = 0.f, d1 = 0.f;
#pragma unroll
                for (int ni = 0; ni < NI; ++ni) {
                    float v = acc[mi][ni][reg];
                    if (head0[ni]) { s0 += v * asv[ni]; d0 += v * adv[ni]; }
                    else           { s1 += v * asv[ni]; d1 += v * adv[ni]; }
                }
#pragma unroll
                for (int off = 1; off < 16; off <<= 1) {
                    s0 += __shfl_xor(s0, off); s1 += __shfl_xor(s1, off);
                    d0 += __shfl_xor(d0, off); d1 += __shfl_xor(d1, off);
                }
                if (mlane == 0) {
                    int rl = wm + mi * 16 + q * 4 + reg;
                    int slot = wave >> 1;
                    sAl[rl][slot][0] = s0; sAl[rl][slot][1] = s1;
                    sAl[rl][slot][2] = d0; sAl[rl][slot][3] = d1;
                }
            }
        }
        __syncthreads();
        if (tid < 128) {
            int row = row0 + tid;
            float v0 = sAl[tid][0][0] + sAl[tid][1][0];
            float v1 = sAl[tid][0][1] + sAl[tid][1][1];
            float v2 = sAl[tid][0][2] + sAl[tid][1][2];
            float v3 = sAl[tid][0][3] + sAl[tid][1][3];
            atomicAdd(&alS[row * 2 + 0], v0);
            atomicAdd(&alS[row * 2 + 1], v1);
            atomicAdd(&alD[row * 2 + 0], v2);
            atomicAdd(&alD[row * 2 + 1], v3);
        }
    }
}

// ------------- fused MLP head: 4 layers in one kernel, 32 rows/block -------------
template<int NI>
__device__ __forceinline__ void mlp_layer(
    const unsigned short* aHi, const unsigned short* aLo, int ldaS, int K,
    const unsigned short* __restrict__ Bhi, const unsigned short* __restrict__ Blo,
    int Kp,
    unsigned short* sBh, unsigned short* sBl,
    const float* __restrict__ bias, int Nbias, int colBase,
    unsigned short* oHi, unsigned short* oLo, int ldo, int Nstore,
    float* __restrict__ gOut, int row0, int relu,
    int wave, int lane)
{
    const int mlane = lane & 15, q = lane >> 4;
    const int wm = (wave & 1) * 16;
    const int wn = (wave >> 1) * (NI * 16);
    f32x4 acc[NI];
#pragma unroll
    for (int b = 0; b < NI; ++b) acc[b] = (f32x4){0.f, 0.f, 0.f, 0.f};

    for (int k0 = 0; k0 < K; k0 += 32) {
        __syncthreads();
        for (int c = wave; c < NI * 2; c += 4) {   // stage B rows (N = NI*32)
            int r = c * 16 + (lane >> 2);
            size_t goff = (size_t)r * Kp + k0 + (lane & 3) * 8;
            load_lds16(Bhi + goff, sBh + c * 512);
            load_lds16(Blo + goff, sBl + c * 512);
        }
        __syncthreads();

        bf16x8 ah, al, bh[NI], bl[NI];
        ah = *(const bf16x8*)(aHi + (wm + mlane) * ldaS + k0 + q * 8);
        al = *(const bf16x8*)(aLo + (wm + mlane) * ldaS + k0 + q * 8);
#pragma unroll
        for (int ni = 0; ni < NI; ++ni) {
            int n = wn + ni * 16 + mlane;
            bh[ni] = *(const bf16x8*)(sBh + n * 32 + q * 8);
            bl[ni] = *(const bf16x8*)(sBl + n * 32 + q * 8);
        }
#pragma unroll
        for (int ni = 0; ni < NI; ++ni) {
            acc[ni] = __builtin_amdgcn_mfma_f32_16x16x32_bf16(ah, bh[ni], acc[ni], 0, 0, 0);
            acc[ni] = __builtin_amdgcn_mfma_f32_16x16x32_bf16(al, bh[ni], acc[ni], 0, 0, 0);
            acc[ni] = __builtin_amdgcn_mfma_f32_16x16x32_bf16(ah, bl[ni], acc[ni], 0, 0, 0);
        }
    }
    __syncthreads();   // all reads of aHi/aLo done before caller overwrites

#pragma unroll
    for (int ni = 0; ni < NI; ++ni) {
        int colg = colBase + wn + ni * 16 + mlane;
        float bv = (colg < Nbias) ? bias[colg] : 0.f;
#pragma unroll
        for (int reg = 0; reg < 4; ++reg) {
            int row = wm + q * 4 + reg;
            float v = acc[ni][reg] + bv;
            if (relu) v = fmaxf(v, 0.f);
            if (gOut) {
                if (colg < 29) gOut[(size_t)(row0 + row) * 29 + colg] = v;
            } else if (colg < Nstore) {
                unsigned short h = f2bf(v);
                oHi[row * ldo + colg] = h;
                oLo[row * ldo + colg] = f2bf(v - bf2f(h));
            }
        }
    }
}

__global__ __launch_bounds__(256) void mlp_fused(
    const unsigned short* __restrict__ actHi, const unsigned short* __restrict__ actLo,
    const unsigned short* __restrict__ L1h, const unsigned short* __restrict__ L1l,
    const unsigned short* __restrict__ L2h, const unsigned short* __restrict__ L2l,
    const unsigned short* __restrict__ L3h, const unsigned short* __restrict__ L3l,
    const unsigned short* __restrict__ L4h, const unsigned short* __restrict__ L4l,
    const float* __restrict__ B1, const float* __restrict__ B2,
    const float* __restrict__ B3, const float* __restrict__ B4,
    float* __restrict__ out)
{
    __shared__ unsigned short b1h[32 * 224], b1l[32 * 224];   // L1 out / L3 out
    __shared__ unsigned short b2h[32 * 128], b2l[32 * 128];   // L2 out
    __shared__ unsigned short sAh[32 * 32],  sAl[32 * 32];    // L1 A staging
    __shared__ unsigned short sBh[128 * 32], sBl[128 * 32];   // B staging
    const int tid = threadIdx.x;
    const int wave = tid >> 6, lane = tid & 63;
    const int row0 = blockIdx.x * 32;
    const int mlane = lane & 15, q = lane >> 4;
    const int wm = (wave & 1) * 16;
    const int wn = (wave >> 1) * 64;

    // ---- layer 1: [32,512] @ L1^T -> b1 [32,224], two 128-col tiles ----
    for (int nt = 0; nt < 2; ++nt) {
        const unsigned short* Bh = L1h + (size_t)nt * 128 * 512;
        const unsigned short* Bl = L1l + (size_t)nt * 128 * 512;
        f32x4 acc[4];
#pragma unroll
        for (int b = 0; b < 4; ++b) acc[b] = (f32x4){0.f, 0.f, 0.f, 0.f};
        for (int k0 = 0; k0 < 512; k0 += 32) {
            __syncthreads();
            for (int c = wave; c < 2; c += 4) {      // A: 32 rows
                int r = c * 16 + (lane >> 2);
                size_t goff = (size_t)(row0 + r) * 512 + k0 + (lane & 3) * 8;
                load_lds16(actHi + goff, sAh + c * 512);
                load_lds16(actLo + goff, sAl + c * 512);
            }
            for (int c = wave; c < 8; c += 4) {      // B: 128 rows
                int r = c * 16 + (lane >> 2);
                size_t goff = (size_t)r * 512 + k0 + (lane & 3) * 8;
                load_lds16(Bh + goff, sBh + c * 512);
                load_lds16(Bl + goff, sBl + c * 512);
            }
            __syncthreads();
            bf16x8 ah = *(const bf16x8*)(sAh + (wm + mlane) * 32 + q * 8);
            bf16x8 al = *(const bf16x8*)(sAl + (wm + mlane) * 32 + q * 8);
#pragma unroll
            for (int ni = 0; ni < 4; ++ni) {
                int n = wn + ni * 16 + mlane;
                bf16x8 bh = *(const bf16x8*)(sBh + n * 32 + q * 8);
                bf16x8 bl = *(const bf16x8*)(sBl + n * 32 + q * 8);
                acc[ni] = __builtin_amdgcn_mfma_f32_16x16x32_bf16(ah, bh, acc[ni], 0, 0, 0);
                acc[ni] = __builtin_amdgcn_mfma_f32_16x16x32_bf16(al, bh, acc[ni], 0, 0, 0);
                acc[ni] = __builtin_amdgcn_mfma_f32_16x16x32_bf16(ah, bl, acc[ni], 0, 0, 0);
            }
        }
        __syncthreads();
#pragma unroll
        for (int ni = 0; ni < 4; ++ni) {
            int colg = nt * 128 + wn + ni * 16 + mlane;
            float bv = (colg < 200) ? B1[colg] : 0.f;
#pragma unroll
            for (int reg = 0; reg < 4; ++reg) {
                int row = wm + q * 4 + reg;
                float v = fmaxf(acc[ni][reg] + bv, 0.f);
                if (colg < 224) {
                    unsigned short h = f2bf(v);
                    b1h[row * 224 + colg] = h;
                    b1l[row * 224 + colg] = f2bf(v - bf2f(h));
                }
            }
        }
    }
    __syncthreads();

    // ---- layer 2: b1[32,224] -> b2[32,128] ----
    mlp_layer<4>(b1h, b1l, 224, 224, L2h, L2l, 224, sBh, sBl,
                 B2, 100, 0, b2h, b2l, 128, 128, nullptr, 0, 1, wave, lane);
    __syncthreads();
    // ---- layer 3: b2[32,128] -> b1[32,128] (reuse, ld 128) ----
    mlp_layer<4>(b2h, b2l, 128, 128, L3h, L3l, 128, sBh, sBl,
                 B3, 100, 0, b1h, b1l, 128, 128, nullptr, 0, 1, wave, lane);
    __syncthreads();
    // ---- layer 4: b1[32,128] -> out[32,29] fp32 ----
    mlp_layer<2>(b1h, b1l, 128, 128, L4h, L4l, 128, sBh, sBl,
                 B4, 29, 0, nullptr, nullptr, 0, 0, out, row0, 0, wave, lane);
}

// ------- weight transpose + bf16 hi/lo decompose (all 8 in one) -------
// N-remap (Pn>0): output rows laid out head-padded [head0 | pad | head1 | pad];
// invalid rows -> zero weights (GEMM then writes exact 0 at pad cols).
// K-remap (Pk>0): input features read from the head-padded act layout
// (per kblk-block: [0,Pk) head0, [Pk,2Pk) head1, rest invalid -> zero rows,
// making act pad values mathematically inert).
struct WtJob {
    const float* W; unsigned short* Whi; unsigned short* Wlo;
    int N, Kp, K, nb0, Cn, Pn, Ck, Pk, kblk;
};
struct WtJobs { WtJob j[8]; };

__global__ void wt_decomp_all(WtJobs jobs)
{
    int b = blockIdx.x;
    int idx = 0;
#pragma unroll
    for (int i = 1; i < 8; ++i)
        if (b >= jobs.j[i].nb0) idx = i;
    WtJob jb = jobs.j[idx];
    int n = b - jb.nb0;
    int norig = n; bool nvalid;
    if (jb.Pn) {
        int hn = n >= jb.Pn;
        int r = hn ? n - jb.Pn : n;
        nvalid = r < jb.Cn;
        norig = hn ? jb.Cn + r : r;
    } else {
        nvalid = n < jb.N;
    }
    for (int k = threadIdx.x; k < jb.Kp; k += 256) {
        int ks; bool kvalid;
        if (jb.Pk) {
            int node = k / jb.kblk;
            int r = k - node * jb.kblk;
            int rr, off;
            if (r < jb.Pk) { rr = r; off = 0; kvalid = rr < jb.Ck; }
            else if (r < 2 * jb.Pk) { rr = r - jb.Pk; off = jb.Ck; kvalid = rr < jb.Ck; }
            else { rr = 0; off = 0; kvalid = false; }
            ks = node * (2 * jb.Ck) + off + rr;
        } else {
            ks = k; kvalid = k < jb.K;
        }
        float v = 0.f;
        if (nvalid && kvalid) v = jb.W[(size_t)ks * jb.N + norig];
        unsigned short h = f2bf(v);
        jb.Whi[(size_t)n * jb.Kp + k] = h;
        jb.Wlo[(size_t)n * jb.Kp + k] = f2bf(v - bf2f(h));
    }
}

// ------- fused stats+gather (all 4 layers, one wave per node) -------
// Head-padded column layout: head boundary at P (multiple of 4) -> per-lane
// head flag hd1 is uniform over the lane's 4 cols -> ONE weight select per
// edge, and pad h-values are exact zeros so no per-element C-masks.
// deg<=64 fast path: chunk-0 lanes own one edge each; e computed once; max
// butterfly; den = butterfly-sum of exp(e-m) (numerator doubles as weight).
// G==1: wave-uniform readlane broadcast + scalar row address.
// EXACT trip counts (no padding) — r7's rounded-up trips added live loads on
// the fill/latency-bound critical path and regressed (114 vs 109 µs).
template<int LPE>
__global__ __launch_bounds__(256) void gat_gather_fused(
    const unsigned short* __restrict__ h16,
    const float* __restrict__ al_s, const float* __restrict__ al_d,
    const int* __restrict__ indptr, const unsigned short* __restrict__ csr_src,
    const float* __restrict__ bias,
    unsigned short* __restrict__ outHi, unsigned short* __restrict__ outLo,
    int ldo, int Nn, int C, int P, int HCpad)
{
    constexpr int G = 64 / LPE;
    const int wave = threadIdx.x >> 6, lane = threadIdx.x & 63;
    const int i = blockIdx.x * 4 + wave;
    if (i >= Nn) return;
    const int start = indptr[i], end = indptr[i + 1];
    const int deg = end - start;
    const float ad0 = al_d[2 * i], ad1 = al_d[2 * i + 1];

    const int l = lane % LPE;
    const int g = lane / LPE;
    const int ch4 = l * 4;
    const bool chA = ch4 < HCpad;
    const bool hd1 = ch4 >= P;          // uniform over the lane's 4 cols
    float a0 = 0.f, a1 = 0.f, a2 = 0.f, a3 = 0.f;

    if (deg <= 64) {
        // ---------------- fast path ----------------
        const int jW = start + lane;
        const bool have = jW < end;
        int ps = 0;
        float e0r = 0.f, e1r = 0.f;
        if (have) {
            ps = csr_src[jW];
            float2 as = *(const float2*)(al_s + 2 * ps);
            e0r = as.x + ad0; e0r = e0r > 0.f ? e0r : NEG_SLOPE * e0r;
            e1r = as.y + ad1; e1r = e1r > 0.f ? e1r : NEG_SLOPE * e1r;
        }
        float m0 = have ? e0r : -1e30f;
        float m1 = have ? e1r : -1e30f;
#pragma unroll
        for (int off = 32; off; off >>= 1) {
            m0 = fmaxf(m0, __shfl_xor(m0, off));
            m1 = fmaxf(m1, __shfl_xor(m1, off));
        }
        float n0 = have ? __expf(e0r - m0) : 0.f;
        float n1 = have ? __expf(e1r - m1) : 0.f;
        float den0 = n0, den1 = n1;
#pragma unroll
        for (int off = 32; off; off >>= 1) {
            den0 += __shfl_xor(den0, off);
            den1 += __shfl_xor(den1, off);
        }
        const float pw0 = n0 * (1.f / den0);
        const float pw1 = n1 * (1.f / den1);

        if constexpr (G == 1) {
            for (int u = 0; u < deg; ++u) {
                float w0 = rl_f(pw0, u);
                float w1 = rl_f(pw1, u);
                float w = hd1 ? w1 : w0;
                int s = __builtin_amdgcn_readlane(ps, u);
                float hx = 0.f, hy = 0.f, hz = 0.f, hw = 0.f;
                if (chA) {
                    f16x4 hv = *(const f16x4*)(h16 + (size_t)s * HCpad + ch4);
                    hx = (float)hv[0]; hy = (float)hv[1];
                    hz = (float)hv[2]; hw = (float)hv[3];
                }
                a0 = fmaf(w, hx, a0);
                a1 = fmaf(w, hy, a1);
                a2 = fmaf(w, hz, a2);
                a3 = fmaf(w, hw, a3);
            }
        } else {
            const int nit = (deg + G - 1) / G;
            for (int u = 0; u < nit; ++u) {
                int idx = u * G + g;               // < 64; lanes>=deg hold w=0
                float w0 = __shfl(pw0, idx);
                float w1 = __shfl(pw1, idx);
                float w = hd1 ? w1 : w0;
                int s = __shfl(ps, idx);
                float hx = 0.f, hy = 0.f, hz = 0.f, hw = 0.f;
                if (chA) {
                    f16x4 hv = *(const f16x4*)(h16 + (size_t)s * HCpad + ch4);
                    hx = (float)hv[0]; hy = (float)hv[1];
                    hz = (float)hv[2]; hw = (float)hv[3];
                }
                a0 = fmaf(w, hx, a0);
                a1 = fmaf(w, hy, a1);
                a2 = fmaf(w, hz, a2);
                a3 = fmaf(w, hw, a3);
            }
        }
    } else {
        // ---------------- fallback: online-stats path (rare) ----------------
        float m0 = -1e30f, m1 = -1e30f, den0 = 0.f, den1 = 0.f;
        for (int j = start + lane; j < end; j += 64) {
            int s = csr_src[j];
            float2 as = *(const float2*)(al_s + 2 * s);
            float e0 = as.x + ad0; e0 = e0 > 0.f ? e0 : NEG_SLOPE * e0;
            float e1 = as.y + ad1; e1 = e1 > 0.f ? e1 : NEG_SLOPE * e1;
            float n0 = fmaxf(m0, e0);
            den0 = den0 * __expf(m0 - n0) + __expf(e0 - n0);
            m0 = n0;
            float n1 = fmaxf(m1, e1);
            den1 = den1 * __expf(m1 - n1) + __expf(e1 - n1);
            m1 = n1;
        }
#pragma unroll
        for (int off = 32; off; off >>= 1) {
            float mo0 = __shfl_xor(m0, off), do0 = __shfl_xor(den0, off);
            float n0 = fmaxf(m0, mo0);
            den0 = den0 * __expf(m0 - n0) + do0 * __expf(mo0 - n0);
            m0 = n0;
            float mo1 = __shfl_xor(m1, off), do1 = __shfl_xor(den1, off);
            float n1 = fmaxf(m1, mo1);
            den1 = den1 * __expf(m1 - n1) + do1 * __expf(mo1 - n1);
            m1 = n1;
        }
        const float inv0 = 1.f / den0, inv1 = 1.f / den1;

        for (int jb = start; jb < end; jb += 64) {
            int jW = jb + lane;
            float pw0 = 0.f, pw1 = 0.f;
            int ps = 0;
            if (jW < end) {
                ps = csr_src[jW];
                float2 as = *(const float2*)(al_s + 2 * ps);
                float e0 = as.x + ad0; e0 = e0 > 0.f ? e0 : NEG_SLOPE * e0;
                float e1 = as.y + ad1; e1 = e1 > 0.f ? e1 : NEG_SLOPE * e1;
                pw0 = __expf(e0 - m0) * inv0;
                pw1 = __expf(e1 - m1) * inv1;
            }
            int nedge = end - jb; if (nedge > 64) nedge = 64;
            int nit = (nedge + G - 1) / G;
            for (int u = 0; u < nit; ++u) {
                int idx = u * G + g;
                float w0 = __shfl(pw0, idx);
                float w1 = __shfl(pw1, idx);
                float w = hd1 ? w1 : w0;
                int s = __shfl(ps, idx);
                float hx = 0.f, hy = 0.f, hz = 0.f, hw = 0.f;
                if (chA) {
                    f16x4 hv = *(const f16x4*)(h16 + (size_t)s * HCpad + ch4);
                    hx = (float)hv[0]; hy = (float)hv[1];
                    hz = (float)hv[2]; hw = (float)hv[3];
                }
                a0 = fmaf(w, hx, a0);
                a1 = fmaf(w, hy, a1);
                a2 = fmaf(w, hz, a2);
                a3 = fmaf(w, hw, a3);
            }
        }
    }

    // ---- shared tail: cross-group reduce, bias+relu (orig-col remap), store ----
#pragma unroll
    for (int off = LPE; off < 64; off <<= 1) {
        a0 += __shfl_xor(a0, off);
        a1 += __shfl_xor(a1, off);
        a2 += __shfl_xor(a2, off);
        a3 += __shfl_xor(a3, off);
    }
    if (g == 0 && chA) {
        float av[4] = {a0, a1, a2, a3};
        unsigned short hi4[4], lo4[4];
#pragma unroll
        for (int k = 0; k < 4; ++k) {
            int colp = ch4 + k;
            int idc = hd1 ? colp - P : colp;
            bool vld = idc < C;
            float bv = vld ? bias[hd1 ? C + idc : idc] : 0.f;
            float v = vld ? fmaxf(av[k] + bv, 0.f) : 0.f;   // pads -> exact 0
            unsigned short h = f2bf(v);
            hi4[k] = h;
            lo4[k] = f2bf(v - bf2f(h));
        }
        ushort4 h = {hi4[0], hi4[1], hi4[2], hi4[3]};
        ushort4 lo = {lo4[0], lo4[1], lo4[2], lo4[3]};
        nt_store_us4(outHi + (size_t)i * ldo + ch4, h);
        nt_store_us4(outLo + (size_t)i * ldo + ch4, lo);
    }
    for (int z = HCpad + lane * 4; z < ldo; z += 256) {
        ushort4 zz; zz.x = zz.y = zz.z = zz.w = 0;
        *(ushort4*)(outHi + (size_t)i * ldo + z) = zz;
        *(ushort4*)(outLo + (size_t)i * ldo + z) = zz;
    }
}

// ---------------- CSR build (with self-loops folded in) ----------------
__global__ void hist_self_k(const int* __restrict__ dst, int E,
                            int* __restrict__ counts, int n)
{
    int gid = blockIdx.x * blockDim.x + threadIdx.x;
    if (gid < E) atomicAdd(&counts[dst[gid]], 1);
    else if (gid < E + n) atomicAdd(&counts[gid - E], 1);
}

__global__ void scan_block_k(const int* __restrict__ in, int* __restrict__ out,
                             int* __restrict__ bsum, int n)
{
    __shared__ int sh[256];
    int gid = blockIdx.x * 256 + threadIdx.x;
    int v = (gid < n) ? in[gid] : 0;
    sh[threadIdx.x] = v;
    __syncthreads();
    for (int off = 1; off < 256; off <<= 1) {
        int t = (threadIdx.x >= off) ? sh[threadIdx.x - off] : 0;
        __syncthreads();
        sh[threadIdx.x] += t;
        __syncthreads();
    }
    int incl = sh[threadIdx.x];
    if (gid < n) out[gid] = incl - v;
    if (threadIdx.x == 255) bsum[blockIdx.x] = incl;
}

__global__ void scan_tops_k(const int* __restrict__ bsum, int* __restrict__ boff)
{
    __shared__ int sh[256];
    int v = bsum[threadIdx.x];
    sh[threadIdx.x] = v;
    __syncthreads();
    for (int off = 1; off < 256; off <<= 1) {
        int t = (threadIdx.x >= off) ? sh[threadIdx.x - off] : 0;
        __syncthreads();
        sh[threadIdx.x] += t;
        __syncthreads();
    }
    boff[threadIdx.x] = sh[threadIdx.x] - v;
}

__global__ void scan_add_k(int* __restrict__ indptr, const int* __restrict__ boff,
                           int n, int Etot)
{
    int gid = blockIdx.x * 256 + threadIdx.x;
    if (gid < n) indptr[gid] += boff[blockIdx.x];
    if (gid == 0) indptr[n] = Etot;
}

__global__ void fill_all_k(const int* __restrict__ src, const int* __restrict__ dst,
                           int E, const int* __restrict__ indptr,
                           int* __restrict__ cursor,
                           unsigned short* __restrict__ csr_src, int n)
{
    int gid = blockIdx.x * blockDim.x + threadIdx.x;
    if (gid < E) {
        int d = dst[gid];
        int pos = atomicAdd(&cursor[d], 1);
        csr_src[indptr[d] + pos] = (unsigned short)src[gid];
    } else if (gid < E + n) {
        int i = gid - E;
        int pos = atomicAdd(&cursor[i], 1);
        csr_src[indptr[i] + pos] = (unsigned short)i;
    }
}

// ---------------- launch ----------------
extern "C" void kernel_launch(void* const* d_in, const int* in_sizes, int n_in,
                              void* d_out, int out_size, void* d_ws, size_t ws_size,
                              hipStream_t stream)
{
    (void)in_sizes; (void)n_in; (void)out_size; (void)ws_size;
    const int N = N_NODES;
    const int E = N_EDGES;
    const int Etot = E + N;

    const float* x = (const float*)d_in[0];
    const int* ei = (const int*)d_in[1];
    const float* Wc[4] = {(const float*)d_in[3], (const float*)d_in[7],
                          (const float*)d_in[11], (const float*)d_in[15]};
    const float* AS[4] = {(const float*)d_in[4], (const float*)d_in[8],
                          (const float*)d_in[12], (const float*)d_in[16]};
    const float* AD[4] = {(const float*)d_in[5], (const float*)d_in[9],
                          (const float*)d_in[13], (const float*)d_in[17]};
    const float* Bc[4] = {(const float*)d_in[6], (const float*)d_in[10],
                          (const float*)d_in[14], (const float*)d_in[18]};
    const float* LW[4] = {(const float*)d_in[19], (const float*)d_in[21],
                          (const float*)d_in[23], (const float*)d_in[25]};
    const float* LB[4] = {(const float*)d_in[20], (const float*)d_in[22],
                          (const float*)d_in[24], (const float*)d_in[26]};

    char* w = (char*)d_ws;
    auto alloc = [&](size_t bytes) -> char* {
        char* p = w; w += (bytes + 255) & ~(size_t)255; return p;
    };
    unsigned short* bufC16 = (unsigned short*)alloc((size_t)N * 256 * 2); // GEMM out, fp16
    unsigned short* actHi = (unsigned short*)alloc((size_t)N * 256 * 2);
    unsigned short* actLo = (unsigned short*)alloc((size_t)N * 256 * 2);
    unsigned short* csr = (unsigned short*)alloc((size_t)Etot * 2);  // u16 src ids
    // alSD (4 layers x [alS|alD]) + counts/cursor: contiguous, single memset
    float* alSD = (float*)alloc((size_t)N * 4 * 4 * 4 + (size_t)N * 2 * 4);
    int* cnt2   = (int*)(alSD + (size_t)N * 16);
    int* counts = cnt2;
    int* cursor = cnt2 + N;
    int* indptr = (int*)alloc((size_t)(N + 8) * 4);
    int* bsum   = (int*)alloc(1024);
    int* boff   = (int*)alloc(1024);

    const int KpConv[4] = {352, 256, 160, 128};
    const int NpConv[4] = {256, 192, 128, 64};
    const int KpLin[4]  = {512, 224, 128, 128};
    const int NpLin[4]  = {256, 128, 128, 64};
    unsigned short *WtHi[4], *WtLo[4], *LtHi[4], *LtLo[4];
    for (int l = 0; l < 4; ++l) {
        WtHi[l] = (unsigned short*)alloc((size_t)NpConv[l] * KpConv[l] * 2);
        WtLo[l] = (unsigned short*)alloc((size_t)NpConv[l] * KpConv[l] * 2);
    }
    for (int l = 0; l < 4; ++l) {
        LtHi[l] = (unsigned short*)alloc((size_t)NpLin[l] * KpLin[l] * 2);
        LtLo[l] = (unsigned short*)alloc((size_t)NpLin[l] * KpLin[l] * 2);
    }

    const int* esrc = ei;
    const int* edst = ei + E;

    // ---- CSR by dst incl. self-loops; zero al buffers + counts in one memset ----
    hipMemsetAsync(alSD, 0, (size_t)N * 4 * 4 * 4 + (size_t)N * 2 * 4, stream);
    hist_self_k<<<(E + N) / 256, 256, 0, stream>>>(edst, E, counts, N);
    scan_block_k<<<N / 256, 256, 0, stream>>>(counts, indptr, bsum, N);
    scan_tops_k<<<1, 256, 0, stream>>>(bsum, boff);
    scan_add_k<<<N / 256, 256, 0, stream>>>(indptr, boff, N, Etot);
    fill_all_k<<<(E + N) / 256, 256, 0, stream>>>(esrc, edst, E, indptr, cursor, csr, N);

    // ---- weight decompose: head-padded N-remap + act-layout K-remap ----
    const int Cc[4] = {125, 75, 50, 30};       // per-head cols
    const int Pc[4] = {128, 76, 52, 32};       // head pad (align 4)
    const int Nc[4] = {250, 150, 100, 60};
    const int Kl[4] = {480, 200, 100, 100};
    const int Nl[4] = {200, 100, 100, 29};
    WtJobs jobs;
    int nb = 0;
    for (int l = 0; l < 4; ++l) {
        WtJob jb;
        jb.W = Wc[l]; jb.Whi = WtHi[l]; jb.Wlo = WtLo[l];
        jb.N = Nc[l]; jb.Kp = KpConv[l]; jb.nb0 = nb;
        jb.Cn = Cc[l]; jb.Pn = Pc[l];
        if (l == 0) { jb.Pk = 0; jb.Ck = 0; jb.kblk = 1; jb.K = 336; }
        else { jb.Pk = Pc[l-1]; jb.Ck = Cc[l-1]; jb.kblk = KpConv[l]; jb.K = 0; }
        jobs.j[l] = jb;
        nb += NpConv[l];
    }
    for (int l = 0; l < 4; ++l) {
        WtJob jb;
        jb.W = LW[l]; jb.Whi = LtHi[l]; jb.Wlo = LtLo[l];
        jb.N = Nl[l]; jb.Kp = KpLin[l]; jb.nb0 = nb;
        jb.Cn = 0; jb.Pn = 0;
        if (l == 0) { jb.Pk = Pc[3]; jb.Ck = Cc[3]; jb.kblk = 64; jb.K = 0; }
        else { jb.Pk = 0; jb.Ck = 0; jb.kblk = 1; jb.K = Kl[l]; }
        jobs.j[4 + l] = jb;
        nb += NpLin[l];
    }
    wt_decomp_all<<<nb, 256, 0, stream>>>(jobs);

    // ---- 4 GAT layers (head-padded fp16 h; stats fused into every gather) ----
    const int HCp[4]  = {256, 152, 104, 64};   // bufC16 stride = 2P
    const int ldoA[4] = {256, 160, 128, 64};   // act stride (= next Kp)
    const int ldaA[4] = {336, 256, 160, 128};  // A leading dim into GEMM
    for (int l = 0; l < 4; ++l) {
        float* alS = alSD + (size_t)l * N * 4;
        float* alD = alS + (size_t)N * 2;
        if (l == 0) {
            gemm_mfma<128><<<dim3(2, N / 128), 256, 0, stream>>>(
                x, 336, nullptr, nullptr, 336, 352,
                WtHi[0], WtLo[0],
                bufC16, HCp[0], HCp[0],
                AS[0], AD[0], alS, alD, Cc[0], Pc[0]);
        } else if (l == 1) {
            gemm_mfma<64><<<dim3(3, N / 128), 256, 0, stream>>>(
                nullptr, 0, actHi, actLo, ldaA[1], KpConv[1],
                WtHi[1], WtLo[1],
                bufC16, HCp[1], HCp[1],
                AS[1], AD[1], alS, alD, Cc[1], Pc[1]);
        } else if (l == 2) {
            gemm_mfma<128><<<dim3(1, N / 128), 256, 0, stream>>>(
                nullptr, 0, actHi, actLo, ldaA[2], KpConv[2],
                WtHi[2], WtLo[2],
                bufC16, HCp[2], HCp[2],
                AS[2], AD[2], alS, alD, Cc[2], Pc[2]);
        } else {
            gemm_mfma<64><<<dim3(1, N / 128), 256, 0, stream>>>(
                nullptr, 0, actHi, actLo, ldaA[3], KpConv[3],
                WtHi[3], WtLo[3],
                bufC16, HCp[3], HCp[3],
                AS[3], AD[3], alS, alD, Cc[3], Pc[3]);
        }
        if (l == 0) {
            gat_gather_fused<64><<<N / 4, 256, 0, stream>>>(
                bufC16, alS, alD, indptr, csr, Bc[0],
                actHi, actLo, ldoA[0], N, Cc[0], Pc[0], HCp[0]);
        } else if (l == 1) {
            gat_gather_fused<64><<<N / 4, 256, 0, stream>>>(
                bufC16, alS, alD, indptr, csr, Bc[1],
                actHi, actLo, ldoA[1], N, Cc[1], Pc[1], HCp[1]);
        } else if (l == 2) {
            gat_gather_fused<32><<<N / 4, 256, 0, stream>>>(
                bufC16, alS, alD, indptr, csr, Bc[2],
                actHi, actLo, ldoA[2], N, Cc[2], Pc[2], HCp[2]);
        } else {
            gat_gather_fused<16><<<N / 4, 256, 0, stream>>>(
                bufC16, alS, alD, indptr, csr, Bc[3],
                actHi, actLo, ldoA[3], N, Cc[3], Pc[3], HCp[3]);
        }
    }

    // ---- MLP head, fused: [8192,480(512 head-padded)] -> 200 -> 100 -> 100 -> 29 ----
    mlp_fused<<<8192 / 32, 256, 0, stream>>>(
        actHi, actLo,
        LtHi[0], LtLo[0], LtHi[1], LtLo[1],
        LtHi[2], LtLo[2], LtHi[3], LtLo[3],
        LB[0], LB[1], LB[2], LB[3],
        (float*)d_out);
}

// Round 11
// 761.693 us; speedup vs baseline: 1.1003x; 1.0831x over previous
//
#include <hip/hip_runtime.h>
#include <hip/hip_bf16.h>
#include <stdint.h>

#define N_NODES 65536
#define N_EDGES (N_NODES * 16)
#define NEG_SLOPE 0.2f

typedef short bf16x8 __attribute__((ext_vector_type(8)));   // 8 bf16 in 4 VGPRs
typedef float f32x4 __attribute__((ext_vector_type(4)));
typedef unsigned int u32x2 __attribute__((ext_vector_type(2)));
typedef _Float16 f16x4 __attribute__((ext_vector_type(4))); // 4 fp16 = 8B

__device__ __forceinline__ unsigned short f2bf(float f) {
    unsigned u = __float_as_uint(f);
    u += 0x7fffu + ((u >> 16) & 1u);       // RNE
    return (unsigned short)(u >> 16);
}
__device__ __forceinline__ float bf2f(unsigned short h) {
    return __uint_as_float(((unsigned)h) << 16);
}
__device__ __forceinline__ unsigned short f2h(float f) {
    _Float16 h = (_Float16)f;              // v_cvt_f16_f32, RNE
    union { _Float16 h; unsigned short u; } cv; cv.h = h; return cv.u;
}
__device__ __forceinline__ float rl_f(float v, int lane) {  // wave-uniform readlane
    return __int_as_float(__builtin_amdgcn_readlane(__float_as_int(v), lane));
}
__device__ __forceinline__ void load_lds16(const void* g, void* l) {
    __builtin_amdgcn_global_load_lds(
        (const __attribute__((address_space(1))) unsigned int*)g,
        (__attribute__((address_space(3))) unsigned int*)l, 16, 0, 0);
}
// nontemporal 8B store of a ushort4 (streaming output; keep L2 for gather rows)
__device__ __forceinline__ void nt_store_us4(unsigned short* p, ushort4 v) {
    u32x2 d;
    d.x = (unsigned)v.x | ((unsigned)v.y << 16);
    d.y = (unsigned)v.z | ((unsigned)v.w << 16);
    __builtin_nontemporal_store(d, (u32x2*)p);
}

// ---------------- MFMA GEMM: C[M,Nw] = A[M,Kp] @ Wt^T ----------------
// A: fp32 (A32 path, converted during staging) or bf16 hi/lo pair.
// Wt transposed [n][Kp] bf16 hi/lo, HEAD-PADDED on N (head0 at [0,P), head1 at
// [P,2P), invalid rows zero) and K-remapped to match the padded act layout.
// Split-bf16: acc += Ahi*Bhi + Alo*Bhi + Ahi*Blo  (fp32 MFMA accumulate).
// C output: fp16 (RNE) in the padded-head layout; pads are exact zeros.
// If asrc != null: per-row attention dots al_s/al_d in FP32 (atomicAdd),
// with padded-col -> original-col remap for the a_s/a_d lookups.
template<int TN>
__global__ __launch_bounds__(256) void gemm_mfma(
    const float* __restrict__ A32, int KA,
    const unsigned short* __restrict__ Ahi, const unsigned short* __restrict__ Alo,
    int lda, int Kp,
    const unsigned short* __restrict__ Bhi, const unsigned short* __restrict__ Blo,
    unsigned short* __restrict__ C16,
    int ldc, int Nw,
    const float* __restrict__ asrc, const float* __restrict__ adst,
    float* __restrict__ alS, float* __restrict__ alD, int Cal, int Pal)
{
    constexpr int NI = TN / 32;                 // N-frags per wave
    __shared__ unsigned short sAhi[128 * 32], sAlo[128 * 32];
    __shared__ unsigned short sBhi[TN * 32],  sBlo[TN * 32];
    __shared__ float sAl[128][2][4];
    const int tid = threadIdx.x;
    const int wave = tid >> 6, lane = tid & 63;
    const int row0 = blockIdx.y * 128;
    const int col0 = blockIdx.x * TN;
    const int wm = (wave & 1) * 64, wn = (wave >> 1) * (TN / 2);
    const int mlane = lane & 15, q = lane >> 4;

    f32x4 acc[4][NI];
#pragma unroll
    for (int a = 0; a < 4; ++a)
#pragma unroll
        for (int b = 0; b < NI; ++b) acc[a][b] = (f32x4){0.f, 0.f, 0.f, 0.f};

    for (int k0 = 0; k0 < Kp; k0 += 32) {
        __syncthreads();
        if (A32) {
            // fp32 -> bf16 hi/lo conversion staging (layer 1 only)
            const int r = tid >> 1, cbase = (tid & 1) * 16;
            const float* Ap = A32 + (size_t)(row0 + r) * lda;
#pragma unroll
            for (int j = 0; j < 4; ++j) {
                int kc = k0 + cbase + j * 4;
                float4 v = make_float4(0.f, 0.f, 0.f, 0.f);
                if (kc < KA) v = *(const float4*)(Ap + kc);
                ushort4 h, l;
                h.x = f2bf(v.x); l.x = f2bf(v.x - bf2f(h.x));
                h.y = f2bf(v.y); l.y = f2bf(v.y - bf2f(h.y));
                h.z = f2bf(v.z); l.z = f2bf(v.z - bf2f(h.z));
                h.w = f2bf(v.w); l.w = f2bf(v.w - bf2f(h.w));
                *(ushort4*)(sAhi + r * 32 + cbase + j * 4) = h;
                *(ushort4*)(sAlo + r * 32 + cbase + j * 4) = l;
            }
        } else {
            // async global->LDS, 16B/lane; LDS dst = wave-uniform base + lane*16
#pragma unroll
            for (int cc = 0; cc < 2; ++cc) {
                int c = wave * 2 + cc;                 // 8 chunks of 16 rows
                int r = c * 16 + (lane >> 2);
                size_t goff = (size_t)(row0 + r) * lda + k0 + (lane & 3) * 8;
                load_lds16(Ahi + goff, sAhi + c * 512);
                load_lds16(Alo + goff, sAlo + c * 512);
            }
        }
        {
#pragma unroll
            for (int cc = 0; cc < TN / 64; ++cc) {
                int c = wave * (TN / 64) + cc;         // TN/16 chunks of 16 rows
                int r = c * 16 + (lane >> 2);
                size_t goff = (size_t)(col0 + r) * Kp + k0 + (lane & 3) * 8;
                load_lds16(Bhi + goff, sBhi + c * 512);
                load_lds16(Blo + goff, sBlo + c * 512);
            }
        }
        __syncthreads();

        bf16x8 ah[4], al[4], bh[NI], bl[NI];
#pragma unroll
        for (int mi = 0; mi < 4; ++mi) {
            int m = wm + mi * 16 + mlane;
            ah[mi] = *(const bf16x8*)(sAhi + m * 32 + q * 8);
            al[mi] = *(const bf16x8*)(sAlo + m * 32 + q * 8);
        }
#pragma unroll
        for (int ni = 0; ni < NI; ++ni) {
            int n = wn + ni * 16 + mlane;
            bh[ni] = *(const bf16x8*)(sBhi + n * 32 + q * 8);
            bl[ni] = *(const bf16x8*)(sBlo + n * 32 + q * 8);
        }
#pragma unroll
        for (int mi = 0; mi < 4; ++mi)
#pragma unroll
            for (int ni = 0; ni < NI; ++ni) {
                acc[mi][ni] = __builtin_amdgcn_mfma_f32_16x16x32_bf16(ah[mi], bh[ni], acc[mi][ni], 0, 0, 0);
                acc[mi][ni] = __builtin_amdgcn_mfma_f32_16x16x32_bf16(al[mi], bh[ni], acc[mi][ni], 0, 0, 0);
                acc[mi][ni] = __builtin_amdgcn_mfma_f32_16x16x32_bf16(ah[mi], bl[ni], acc[mi][ni], 0, 0, 0);
            }
    }

    // epilogue: C/D frag layout col=lane&15, row=(lane>>4)*4+reg; fp16 store
#pragma unroll
    for (int ni = 0; ni < NI; ++ni) {
        int col = col0 + wn + ni * 16 + mlane;
        if (col >= Nw) continue;
#pragma unroll
        for (int mi = 0; mi < 4; ++mi) {
#pragma unroll
            for (int reg = 0; reg < 4; ++reg) {
                int row = row0 + wm + mi * 16 + q * 4 + reg;
                C16[(size_t)row * ldc + col] = f2h(acc[mi][ni][reg]);
            }
        }
    }

    // fused attention-logit dots (padded-col -> orig-col remap for a_s/a_d)
    if (asrc) {
        float asv[NI], adv[NI];
        bool head0[NI];
#pragma unroll
        for (int ni = 0; ni < NI; ++ni) {
            int col = col0 + wn + ni * 16 + mlane;
            int hd = col >= Pal;
            int idc = hd ? col - Pal : col;
            bool valid = idc < Cal;
            head0[ni] = !hd;
            int borig = hd ? Cal + idc : idc;
            asv[ni] = valid ? asrc[borig] : 0.f;
            adv[ni] = valid ? adst[borig] : 0.f;
        }
#pragma unroll
        for (int mi = 0; mi < 4; ++mi) {
#pragma unroll
            for (int reg = 0; reg < 4; ++reg) {
                float s0 = 0.f, s1 = 0.f, d0 = 0.f, d1 = 0.f;
#pragma unroll
                for (int ni = 0; ni < NI; ++ni) {
                    float v = acc[mi][ni][reg];
                    if (head0[ni]) { s0 += v * asv[ni]; d0 += v * adv[ni]; }
                    else           { s1 += v * asv[ni]; d1 += v * adv[ni]; }
                }
#pragma unroll
                for (int off = 1; off < 16; off <<= 1) {
                    s0 += __shfl_xor(s0, off); s1 += __shfl_xor(s1, off);
                    d0 += __shfl_xor(d0, off); d1 += __shfl_xor(d1, off);
                }
                if (mlane == 0) {
                    int rl = wm + mi * 16 + q * 4 + reg;
                    int slot = wave >> 1;
                    sAl[rl][slot][0] = s0; sAl[rl][slot][1] = s1;
                    sAl[rl][slot][2] = d0; sAl[rl][slot][3] = d1;
                }
            }
        }
        __syncthreads();
        if (tid < 128) {
            int row = row0 + tid;
            float v0 = sAl[tid][0][0] + sAl[tid][1][0];
            float v1 = sAl[tid][0][1] + sAl[tid][1][1];
            float v2 = sAl[tid][0][2] + sAl[tid][1][2];
            float v3 = sAl[tid][0][3] + sAl[tid][1][3];
            atomicAdd(&alS[row * 2 + 0], v0);
            atomicAdd(&alS[row * 2 + 1], v1);
            atomicAdd(&alD[row * 2 + 0], v2);
            atomicAdd(&alD[row * 2 + 1], v3);
        }
    }
}

// ------------- fused MLP head: 4 layers in one kernel, 32 rows/block -------------
template<int NI>
__device__ __forceinline__ void mlp_layer(
    const unsigned short* aHi, const unsigned short* aLo, int ldaS, int K,
    const unsigned short* __restrict__ Bhi, const unsigned short* __restrict__ Blo,
    int Kp,
    unsigned short* sBh, unsigned short* sBl,
    const float* __restrict__ bias, int Nbias, int colBase,
    unsigned short* oHi, unsigned short* oLo, int ldo, int Nstore,
    float* __restrict__ gOut, int row0, int relu,
    int wave, int lane)
{
    const int mlane = lane & 15, q = lane >> 4;
    const int wm = (wave & 1) * 16;
    const int wn = (wave >> 1) * (NI * 16);
    f32x4 acc[NI];
#pragma unroll
    for (int b = 0; b < NI; ++b) acc[b] = (f32x4){0.f, 0.f, 0.f, 0.f};

    for (int k0 = 0; k0 < K; k0 += 32) {
        __syncthreads();
        for (int c = wave; c < NI * 2; c += 4) {   // stage B rows (N = NI*32)
            int r = c * 16 + (lane >> 2);
            size_t goff = (size_t)r * Kp + k0 + (lane & 3) * 8;
            load_lds16(Bhi + goff, sBh + c * 512);
            load_lds16(Blo + goff, sBl + c * 512);
        }
        __syncthreads();

        bf16x8 ah, al, bh[NI], bl[NI];
        ah = *(const bf16x8*)(aHi + (wm + mlane) * ldaS + k0 + q * 8);
        al = *(const bf16x8*)(aLo + (wm + mlane) * ldaS + k0 + q * 8);
#pragma unroll
        for (int ni = 0; ni < NI; ++ni) {
            int n = wn + ni * 16 + mlane;
            bh[ni] = *(const bf16x8*)(sBh + n * 32 + q * 8);
            bl[ni] = *(const bf16x8*)(sBl + n * 32 + q * 8);
        }
#pragma unroll
        for (int ni = 0; ni < NI; ++ni) {
            acc[ni] = __builtin_amdgcn_mfma_f32_16x16x32_bf16(ah, bh[ni], acc[ni], 0, 0, 0);
            acc[ni] = __builtin_amdgcn_mfma_f32_16x16x32_bf16(al, bh[ni], acc[ni], 0, 0, 0);
            acc[ni] = __builtin_amdgcn_mfma_f32_16x16x32_bf16(ah, bl[ni], acc[ni], 0, 0, 0);
        }
    }
    __syncthreads();   // all reads of aHi/aLo done before caller overwrites

#pragma unroll
    for (int ni = 0; ni < NI; ++ni) {
        int colg = colBase + wn + ni * 16 + mlane;
        float bv = (colg < Nbias) ? bias[colg] : 0.f;
#pragma unroll
        for (int reg = 0; reg < 4; ++reg) {
            int row = wm + q * 4 + reg;
            float v = acc[ni][reg] + bv;
            if (relu) v = fmaxf(v, 0.f);
            if (gOut) {
                if (colg < 29) gOut[(size_t)(row0 + row) * 29 + colg] = v;
            } else if (colg < Nstore) {
                unsigned short h = f2bf(v);
                oHi[row * ldo + colg] = h;
                oLo[row * ldo + colg] = f2bf(v - bf2f(h));
            }
        }
    }
}

__global__ __launch_bounds__(256) void mlp_fused(
    const unsigned short* __restrict__ actHi, const unsigned short* __restrict__ actLo,
    const unsigned short* __restrict__ L1h, const unsigned short* __restrict__ L1l,
    const unsigned short* __restrict__ L2h, const unsigned short* __restrict__ L2l,
    const unsigned short* __restrict__ L3h, const unsigned short* __restrict__ L3l,
    const unsigned short* __restrict__ L4h, const unsigned short* __restrict__ L4l,
    const float* __restrict__ B1, const float* __restrict__ B2,
    const float* __restrict__ B3, const float* __restrict__ B4,
    float* __restrict__ out)
{
    __shared__ unsigned short b1h[32 * 224], b1l[32 * 224];   // L1 out / L3 out
    __shared__ unsigned short b2h[32 * 128], b2l[32 * 128];   // L2 out
    __shared__ unsigned short sAh[32 * 32],  sAl[32 * 32];    // L1 A staging
    __shared__ unsigned short sBh[128 * 32], sBl[128 * 32];   // B staging
    const int tid = threadIdx.x;
    const int wave = tid >> 6, lane = tid & 63;
    const int row0 = blockIdx.x * 32;
    const int mlane = lane & 15, q = lane >> 4;
    const int wm = (wave & 1) * 16;
    const int wn = (wave >> 1) * 64;

    // ---- layer 1: [32,512] @ L1^T -> b1 [32,224], two 128-col tiles ----
    for (int nt = 0; nt < 2; ++nt) {
        const unsigned short* Bh = L1h + (size_t)nt * 128 * 512;
        const unsigned short* Bl = L1l + (size_t)nt * 128 * 512;
        f32x4 acc[4];
#pragma unroll
        for (int b = 0; b < 4; ++b) acc[b] = (f32x4){0.f, 0.f, 0.f, 0.f};
        for (int k0 = 0; k0 < 512; k0 += 32) {
            __syncthreads();
            for (int c = wave; c < 2; c += 4) {      // A: 32 rows
                int r = c * 16 + (lane >> 2);
                size_t goff = (size_t)(row0 + r) * 512 + k0 + (lane & 3) * 8;
                load_lds16(actHi + goff, sAh + c * 512);
                load_lds16(actLo + goff, sAl + c * 512);
            }
            for (int c = wave; c < 8; c += 4) {      // B: 128 rows
                int r = c * 16 + (lane >> 2);
                size_t goff = (size_t)r * 512 + k0 + (lane & 3) * 8;
                load_lds16(Bh + goff, sBh + c * 512);
                load_lds16(Bl + goff, sBl + c * 512);
            }
            __syncthreads();
            bf16x8 ah = *(const bf16x8*)(sAh + (wm + mlane) * 32 + q * 8);
            bf16x8 al = *(const bf16x8*)(sAl + (wm + mlane) * 32 + q * 8);
#pragma unroll
            for (int ni = 0; ni < 4; ++ni) {
                int n = wn + ni * 16 + mlane;
                bf16x8 bh = *(const bf16x8*)(sBh + n * 32 + q * 8);
                bf16x8 bl = *(const bf16x8*)(sBl + n * 32 + q * 8);
                acc[ni] = __builtin_amdgcn_mfma_f32_16x16x32_bf16(ah, bh, acc[ni], 0, 0, 0);
                acc[ni] = __builtin_amdgcn_mfma_f32_16x16x32_bf16(al, bh, acc[ni], 0, 0, 0);
                acc[ni] = __builtin_amdgcn_mfma_f32_16x16x32_bf16(ah, bl, acc[ni], 0, 0, 0);
            }
        }
        __syncthreads();
#pragma unroll
        for (int ni = 0; ni < 4; ++ni) {
            int colg = nt * 128 + wn + ni * 16 + mlane;
            float bv = (colg < 200) ? B1[colg] : 0.f;
#pragma unroll
            for (int reg = 0; reg < 4; ++reg) {
                int row = wm + q * 4 + reg;
                float v = fmaxf(acc[ni][reg] + bv, 0.f);
                if (colg < 224) {
                    unsigned short h = f2bf(v);
                    b1h[row * 224 + colg] = h;
                    b1l[row * 224 + colg] = f2bf(v - bf2f(h));
                }
            }
        }
    }
    __syncthreads();

    // ---- layer 2: b1[32,224] -> b2[32,128] ----
    mlp_layer<4>(b1h, b1l, 224, 224, L2h, L2l, 224, sBh, sBl,
                 B2, 100, 0, b2h, b2l, 128, 128, nullptr, 0, 1, wave, lane);
    __syncthreads();
    // ---- layer 3: b2[32,128] -> b1[32,128] (reuse, ld 128) ----
    mlp_layer<4>(b2h, b2l, 128, 128, L3h, L3l, 128, sBh, sBl,
                 B3, 100, 0, b1h, b1l, 128, 128, nullptr, 0, 1, wave, lane);
    __syncthreads();
    // ---- layer 4: b1[32,128] -> out[32,29] fp32 ----
    mlp_layer<2>(b1h, b1l, 128, 128, L4h, L4l, 128, sBh, sBl,
                 B4, 29, 0, nullptr, nullptr, 0, 0, out, row0, 0, wave, lane);
}

// ------- weight transpose + bf16 hi/lo decompose (all 8 in one) -------
// N-remap (Pn>0): output rows laid out head-padded [head0 | pad | head1 | pad];
// invalid rows -> zero weights (GEMM then writes exact 0 at pad cols).
// K-remap (Pk>0): input features read from the head-padded act layout
// (per kblk-block: [0,Pk) head0, [Pk,2Pk) head1, rest invalid -> zero rows,
// making act pad values mathematically inert).
struct WtJob {
    const float* W; unsigned short* Whi; unsigned short* Wlo;
    int N, Kp, K, nb0, Cn, Pn, Ck, Pk, kblk;
};
struct WtJobs { WtJob j[8]; };

__global__ void wt_decomp_all(WtJobs jobs)
{
    int b = blockIdx.x;
    int idx = 0;
#pragma unroll
    for (int i = 1; i < 8; ++i)
        if (b >= jobs.j[i].nb0) idx = i;
    WtJob jb = jobs.j[idx];
    int n = b - jb.nb0;
    int norig = n; bool nvalid;
    if (jb.Pn) {
        int hn = n >= jb.Pn;
        int r = hn ? n - jb.Pn : n;
        nvalid = r < jb.Cn;
        norig = hn ? jb.Cn + r : r;
    } else {
        nvalid = n < jb.N;
    }
    for (int k = threadIdx.x; k < jb.Kp; k += 256) {
        int ks; bool kvalid;
        if (jb.Pk) {
            int node = k / jb.kblk;
            int r = k - node * jb.kblk;
            int rr, off;
            if (r < jb.Pk) { rr = r; off = 0; kvalid = rr < jb.Ck; }
            else if (r < 2 * jb.Pk) { rr = r - jb.Pk; off = jb.Ck; kvalid = rr < jb.Ck; }
            else { rr = 0; off = 0; kvalid = false; }
            ks = node * (2 * jb.Ck) + off + rr;
        } else {
            ks = k; kvalid = k < jb.K;
        }
        float v = 0.f;
        if (nvalid && kvalid) v = jb.W[(size_t)ks * jb.N + norig];
        unsigned short h = f2bf(v);
        jb.Whi[(size_t)n * jb.Kp + k] = h;
        jb.Wlo[(size_t)n * jb.Kp + k] = f2bf(v - bf2f(h));
    }
}

// ------- fused stats+gather (all 4 layers, one wave per node) -------
// Head-padded column layout: single receiver-side head select per edge.
// CORRECTNESS NOTE (r10 bug): the select must happen AFTER the cross-lane
// broadcast, on the receiving lane (hd1 is a property of the receiver's
// columns). Broadcasting a pre-selected weight delivers the edge-lane's
// head choice to every receiver -> wrong head weights (absmax 4e-3).
// Edge loop is software-pipelined (4-deep G==1, 2-deep G>1), exact trips:
// same loads, same FP order per accumulator (bitwise identical to r9).
template<int LPE>
__global__ __launch_bounds__(256) void gat_gather_fused(
    const unsigned short* __restrict__ h16,
    const float* __restrict__ al_s, const float* __restrict__ al_d,
    const int* __restrict__ indptr, const unsigned short* __restrict__ csr_src,
    const float* __restrict__ bias,
    unsigned short* __restrict__ outHi, unsigned short* __restrict__ outLo,
    int ldo, int Nn, int C, int P, int HCpad)
{
    constexpr int G = 64 / LPE;
    const int wave = threadIdx.x >> 6, lane = threadIdx.x & 63;
    const int i = blockIdx.x * 4 + wave;
    if (i >= Nn) return;
    const int start = indptr[i], end = indptr[i + 1];
    const int deg = end - start;
    const float ad0 = al_d[2 * i], ad1 = al_d[2 * i + 1];

    const int l = lane % LPE;
    const int g = lane / LPE;
    const int ch4 = l * 4;
    const bool chA = ch4 < HCpad;
    const bool hd1 = ch4 >= P;          // uniform over the lane's 4 cols
    float a0 = 0.f, a1 = 0.f, a2 = 0.f, a3 = 0.f;
    const unsigned short* hbase = h16 + ch4;

    if (deg <= 64) {
        // ---------------- fast path ----------------
        const int jW = start + lane;
        const bool have = jW < end;
        int ps = 0;
        float e0r = 0.f, e1r = 0.f;
        if (have) {
            ps = csr_src[jW];
            float2 as = *(const float2*)(al_s + 2 * ps);
            e0r = as.x + ad0; e0r = e0r > 0.f ? e0r : NEG_SLOPE * e0r;
            e1r = as.y + ad1; e1r = e1r > 0.f ? e1r : NEG_SLOPE * e1r;
        }
        float m0 = have ? e0r : -1e30f;
        float m1 = have ? e1r : -1e30f;
#pragma unroll
        for (int off = 32; off; off >>= 1) {
            m0 = fmaxf(m0, __shfl_xor(m0, off));
            m1 = fmaxf(m1, __shfl_xor(m1, off));
        }
        float n0 = have ? __expf(e0r - m0) : 0.f;
        float n1 = have ? __expf(e1r - m1) : 0.f;
        float den0 = n0, den1 = n1;
#pragma unroll
        for (int off = 32; off; off >>= 1) {
            den0 += __shfl_xor(den0, off);
            den1 += __shfl_xor(den1, off);
        }
        const float pw0 = n0 * (1.f / den0);
        const float pw1 = n1 * (1.f / den1);

        if constexpr (G == 1) {
            int u = 0;
            // 4-deep pipeline: issue 4 independent row loads, then consume in
            // exact edge order u..u+3 per accumulator. Weight select on the
            // RECEIVER side, after broadcast.
            for (; u + 3 < deg; u += 4) {
                int s0 = __builtin_amdgcn_readlane(ps, u);
                int s1 = __builtin_amdgcn_readlane(ps, u + 1);
                int s2 = __builtin_amdgcn_readlane(ps, u + 2);
                int s3 = __builtin_amdgcn_readlane(ps, u + 3);
                f16x4 h0 = {}, h1 = {}, h2 = {}, h3 = {};
                if (chA) {
                    h0 = *(const f16x4*)(hbase + (size_t)s0 * HCpad);
                    h1 = *(const f16x4*)(hbase + (size_t)s1 * HCpad);
                    h2 = *(const f16x4*)(hbase + (size_t)s2 * HCpad);
                    h3 = *(const f16x4*)(hbase + (size_t)s3 * HCpad);
                }
                float w0 = hd1 ? rl_f(pw1, u)     : rl_f(pw0, u);
                float w1 = hd1 ? rl_f(pw1, u + 1) : rl_f(pw0, u + 1);
                float w2 = hd1 ? rl_f(pw1, u + 2) : rl_f(pw0, u + 2);
                float w3 = hd1 ? rl_f(pw1, u + 3) : rl_f(pw0, u + 3);
                a0 = fmaf(w0, (float)h0[0], a0);
                a1 = fmaf(w0, (float)h0[1], a1);
                a2 = fmaf(w0, (float)h0[2], a2);
                a3 = fmaf(w0, (float)h0[3], a3);
                a0 = fmaf(w1, (float)h1[0], a0);
                a1 = fmaf(w1, (float)h1[1], a1);
                a2 = fmaf(w1, (float)h1[2], a2);
                a3 = fmaf(w1, (float)h1[3], a3);
                a0 = fmaf(w2, (float)h2[0], a0);
                a1 = fmaf(w2, (float)h2[1], a1);
                a2 = fmaf(w2, (float)h2[2], a2);
                a3 = fmaf(w2, (float)h2[3], a3);
                a0 = fmaf(w3, (float)h3[0], a0);
                a1 = fmaf(w3, (float)h3[1], a1);
                a2 = fmaf(w3, (float)h3[2], a2);
                a3 = fmaf(w3, (float)h3[3], a3);
            }
            for (; u < deg; ++u) {
                int s = __builtin_amdgcn_readlane(ps, u);
                f16x4 hv = {};
                if (chA) hv = *(const f16x4*)(hbase + (size_t)s * HCpad);
                float w = hd1 ? rl_f(pw1, u) : rl_f(pw0, u);
                a0 = fmaf(w, (float)hv[0], a0);
                a1 = fmaf(w, (float)hv[1], a1);
                a2 = fmaf(w, (float)hv[2], a2);
                a3 = fmaf(w, (float)hv[3], a3);
            }
        } else {
            const int nit = (deg + G - 1) / G;
            int u = 0;
            // 2-deep pipeline: two group-iterations in flight.
            for (; u + 1 < nit; u += 2) {
                int idxA = u * G + g;
                int idxB = (u + 1) * G + g;        // < 64
                float wA0 = __shfl(pw0, idxA), wA1 = __shfl(pw1, idxA);
                float wB0 = __shfl(pw0, idxB), wB1 = __shfl(pw1, idxB);
                float wA = hd1 ? wA1 : wA0;
                float wB = hd1 ? wB1 : wB0;
                int sA = __shfl(ps, idxA);
                int sB = __shfl(ps, idxB);
                f16x4 hA = {}, hB = {};
                if (chA) {
                    hA = *(const f16x4*)(hbase + (size_t)sA * HCpad);
                    hB = *(const f16x4*)(hbase + (size_t)sB * HCpad);
                }
                a0 = fmaf(wA, (float)hA[0], a0);
                a1 = fmaf(wA, (float)hA[1], a1);
                a2 = fmaf(wA, (float)hA[2], a2);
                a3 = fmaf(wA, (float)hA[3], a3);
                a0 = fmaf(wB, (float)hB[0], a0);
                a1 = fmaf(wB, (float)hB[1], a1);
                a2 = fmaf(wB, (float)hB[2], a2);
                a3 = fmaf(wB, (float)hB[3], a3);
            }
            for (; u < nit; ++u) {
                int idx = u * G + g;
                float w0 = __shfl(pw0, idx), w1 = __shfl(pw1, idx);
                float w = hd1 ? w1 : w0;
                int s = __shfl(ps, idx);
                f16x4 hv = {};
                if (chA) hv = *(const f16x4*)(hbase + (size_t)s * HCpad);
                a0 = fmaf(w, (float)hv[0], a0);
                a1 = fmaf(w, (float)hv[1], a1);
                a2 = fmaf(w, (float)hv[2], a2);
                a3 = fmaf(w, (float)hv[3], a3);
            }
        }
    } else {
        // ---------------- fallback: online-stats path (rare) ----------------
        float m0 = -1e30f, m1 = -1e30f, den0 = 0.f, den1 = 0.f;
        for (int j = start + lane; j < end; j += 64) {
            int s = csr_src[j];
            float2 as = *(const float2*)(al_s + 2 * s);
            float e0 = as.x + ad0; e0 = e0 > 0.f ? e0 : NEG_SLOPE * e0;
            float e1 = as.y + ad1; e1 = e1 > 0.f ? e1 : NEG_SLOPE * e1;
            float n0 = fmaxf(m0, e0);
            den0 = den0 * __expf(m0 - n0) + __expf(e0 - n0);
            m0 = n0;
            float n1 = fmaxf(m1, e1);
            den1 = den1 * __expf(m1 - n1) + __expf(e1 - n1);
            m1 = n1;
        }
#pragma unroll
        for (int off = 32; off; off >>= 1) {
            float mo0 = __shfl_xor(m0, off), do0 = __shfl_xor(den0, off);
            float n0 = fmaxf(m0, mo0);
            den0 = den0 * __expf(m0 - n0) + do0 * __expf(mo0 - n0);
            m0 = n0;
            float mo1 = __shfl_xor(m1, off), do1 = __shfl_xor(den1, off);
            float n1 = fmaxf(m1, mo1);
            den1 = den1 * __expf(m1 - n1) + do1 * __expf(mo1 - n1);
            m1 = n1;
        }
        const float inv0 = 1.f / den0, inv1 = 1.f / den1;

        for (int jb = start; jb < end; jb += 64) {
            int jW = jb + lane;
            float pw0 = 0.f, pw1 = 0.f;
            int ps = 0;
            if (jW < end) {
                ps = csr_src[jW];
                float2 as = *(const float2*)(al_s + 2 * ps);
                float e0 = as.x + ad0; e0 = e0 > 0.f ? e0 : NEG_SLOPE * e0;
                float e1 = as.y + ad1; e1 = e1 > 0.f ? e1 : NEG_SLOPE * e1;
                pw0 = __expf(e0 - m0) * inv0;
                pw1 = __expf(e1 - m1) * inv1;
            }
            int nedge = end - jb; if (nedge > 64) nedge = 64;
            int nit = (nedge + G - 1) / G;
            for (int u = 0; u < nit; ++u) {
                int idx = u * G + g;
                float w0 = __shfl(pw0, idx), w1 = __shfl(pw1, idx);
                float w = hd1 ? w1 : w0;
                int s = __shfl(ps, idx);
                f16x4 hv = {};
                if (chA) hv = *(const f16x4*)(hbase + (size_t)s * HCpad);
                a0 = fmaf(w, (float)hv[0], a0);
                a1 = fmaf(w, (float)hv[1], a1);
                a2 = fmaf(w, (float)hv[2], a2);
                a3 = fmaf(w, (float)hv[3], a3);
            }
        }
    }

    // ---- shared tail: cross-group reduce, bias+relu (orig-col remap), store ----
#pragma unroll
    for (int off = LPE; off < 64; off <<= 1) {
        a0 += __shfl_xor(a0, off);
        a1 += __shfl_xor(a1, off);
        a2 += __shfl_xor(a2, off);
        a3 += __shfl_xor(a3, off);
    }
    if (g == 0 && chA) {
        float av[4] = {a0, a1, a2, a3};
        unsigned short hi4[4], lo4[4];
#pragma unroll
        for (int k = 0; k < 4; ++k) {
            int colp = ch4 + k;
            int idc = hd1 ? colp - P : colp;
            bool vld = idc < C;
            float bv = vld ? bias[hd1 ? C + idc : idc] : 0.f;
            float v = vld ? fmaxf(av[k] + bv, 0.f) : 0.f;   // pads -> exact 0
            unsigned short h = f2bf(v);
            hi4[k] = h;
            lo4[k] = f2bf(v - bf2f(h));
        }
        ushort4 h = {hi4[0], hi4[1], hi4[2], hi4[3]};
        ushort4 lo = {lo4[0], lo4[1], lo4[2], lo4[3]};
        nt_store_us4(outHi + (size_t)i * ldo + ch4, h);
        nt_store_us4(outLo + (size_t)i * ldo + ch4, lo);
    }
    for (int z = HCpad + lane * 4; z < ldo; z += 256) {
        ushort4 zz; zz.x = zz.y = zz.z = zz.w = 0;
        *(ushort4*)(outHi + (size_t)i * ldo + z) = zz;
        *(ushort4*)(outLo + (size_t)i * ldo + z) = zz;
    }
}

// ---------------- CSR build (with self-loops folded in) ----------------
__global__ void hist_self_k(const int* __restrict__ dst, int E,
                            int* __restrict__ counts, int n)
{
    int gid = blockIdx.x * blockDim.x + threadIdx.x;
    if (gid < E) atomicAdd(&counts[dst[gid]], 1);
    else if (gid < E + n) atomicAdd(&counts[gid - E], 1);
}

__global__ void scan_block_k(const int* __restrict__ in, int* __restrict__ out,
                             int* __restrict__ bsum, int n)
{
    __shared__ int sh[256];
    int gid = blockIdx.x * 256 + threadIdx.x;
    int v = (gid < n) ? in[gid] : 0;
    sh[threadIdx.x] = v;
    __syncthreads();
    for (int off = 1; off < 256; off <<= 1) {
        int t = (threadIdx.x >= off) ? sh[threadIdx.x - off] : 0;
        __syncthreads();
        sh[threadIdx.x] += t;
        __syncthreads();
    }
    int incl = sh[threadIdx.x];
    if (gid < n) out[gid] = incl - v;
    if (threadIdx.x == 255) bsum[blockIdx.x] = incl;
}

__global__ void scan_tops_k(const int* __restrict__ bsum, int* __restrict__ boff)
{
    __shared__ int sh[256];
    int v = bsum[threadIdx.x];
    sh[threadIdx.x] = v;
    __syncthreads();
    for (int off = 1; off < 256; off <<= 1) {
        int t = (threadIdx.x >= off) ? sh[threadIdx.x - off] : 0;
        __syncthreads();
        sh[threadIdx.x] += t;
        __syncthreads();
    }
    boff[threadIdx.x] = sh[threadIdx.x] - v;
}

__global__ void scan_add_k(int* __restrict__ indptr, const int* __restrict__ boff,
                           int n, int Etot)
{
    int gid = blockIdx.x * 256 + threadIdx.x;
    if (gid < n) indptr[gid] += boff[blockIdx.x];
    if (gid == 0) indptr[n] = Etot;
}

__global__ void fill_all_k(const int* __restrict__ src, const int* __restrict__ dst,
                           int E, const int* __restrict__ indptr,
                           int* __restrict__ cursor,
                           unsigned short* __restrict__ csr_src, int n)
{
    int gid = blockIdx.x * blockDim.x + threadIdx.x;
    if (gid < E) {
        int d = dst[gid];
        int pos = atomicAdd(&cursor[d], 1);
        csr_src[indptr[d] + pos] = (unsigned short)src[gid];
    } else if (gid < E + n) {
        int i = gid - E;
        int pos = atomicAdd(&cursor[i], 1);
        csr_src[indptr[i] + pos] = (unsigned short)i;
    }
}

// ---------------- launch ----------------
extern "C" void kernel_launch(void* const* d_in, const int* in_sizes, int n_in,
                              void* d_out, int out_size, void* d_ws, size_t ws_size,
                              hipStream_t stream)
{
    (void)in_sizes; (void)n_in; (void)out_size; (void)ws_size;
    const int N = N_NODES;
    const int E = N_EDGES;
    const int Etot = E + N;

    const float* x = (const float*)d_in[0];
    const int* ei = (const int*)d_in[1];
    const float* Wc[4] = {(const float*)d_in[3], (const float*)d_in[7],
                          (const float*)d_in[11], (const float*)d_in[15]};
    const float* AS[4] = {(const float*)d_in[4], (const float*)d_in[8],
                          (const float*)d_in[12], (const float*)d_in[16]};
    const float* AD[4] = {(const float*)d_in[5], (const float*)d_in[9],
                          (const float*)d_in[13], (const float*)d_in[17]};
    const float* Bc[4] = {(const float*)d_in[6], (const float*)d_in[10],
                          (const float*)d_in[14], (const float*)d_in[18]};
    const float* LW[4] = {(const float*)d_in[19], (const float*)d_in[21],
                          (const float*)d_in[23], (const float*)d_in[25]};
    const float* LB[4] = {(const float*)d_in[20], (const float*)d_in[22],
                          (const float*)d_in[24], (const float*)d_in[26]};

    char* w = (char*)d_ws;
    auto alloc = [&](size_t bytes) -> char* {
        char* p = w; w += (bytes + 255) & ~(size_t)255; return p;
    };
    unsigned short* bufC16 = (unsigned short*)alloc((size_t)N * 256 * 2); // GEMM out, fp16
    unsigned short* actHi = (unsigned short*)alloc((size_t)N * 256 * 2);
    unsigned short* actLo = (unsigned short*)alloc((size_t)N * 256 * 2);
    unsigned short* csr = (unsigned short*)alloc((size_t)Etot * 2);  // u16 src ids
    // alSD (4 layers x [alS|alD]) + counts/cursor: contiguous, single memset
    float* alSD = (float*)alloc((size_t)N * 4 * 4 * 4 + (size_t)N * 2 * 4);
    int* cnt2   = (int*)(alSD + (size_t)N * 16);
    int* counts = cnt2;
    int* cursor = cnt2 + N;
    int* indptr = (int*)alloc((size_t)(N + 8) * 4);
    int* bsum   = (int*)alloc(1024);
    int* boff   = (int*)alloc(1024);

    const int KpConv[4] = {352, 256, 160, 128};
    const int NpConv[4] = {256, 192, 128, 64};
    const int KpLin[4]  = {512, 224, 128, 128};
    const int NpLin[4]  = {256, 128, 128, 64};
    unsigned short *WtHi[4], *WtLo[4], *LtHi[4], *LtLo[4];
    for (int l = 0; l < 4; ++l) {
        WtHi[l] = (unsigned short*)alloc((size_t)NpConv[l] * KpConv[l] * 2);
        WtLo[l] = (unsigned short*)alloc((size_t)NpConv[l] * KpConv[l] * 2);
    }
    for (int l = 0; l < 4; ++l) {
        LtHi[l] = (unsigned short*)alloc((size_t)NpLin[l] * KpLin[l] * 2);
        LtLo[l] = (unsigned short*)alloc((size_t)NpLin[l] * KpLin[l] * 2);
    }

    const int* esrc = ei;
    const int* edst = ei + E;

    // ---- CSR by dst incl. self-loops; zero al buffers + counts in one memset ----
    hipMemsetAsync(alSD, 0, (size_t)N * 4 * 4 * 4 + (size_t)N * 2 * 4, stream);
    hist_self_k<<<(E + N) / 256, 256, 0, stream>>>(edst, E, counts, N);
    scan_block_k<<<N / 256, 256, 0, stream>>>(counts, indptr, bsum, N);
    scan_tops_k<<<1, 256, 0, stream>>>(bsum, boff);
    scan_add_k<<<N / 256, 256, 0, stream>>>(indptr, boff, N, Etot);
    fill_all_k<<<(E + N) / 256, 256, 0, stream>>>(esrc, edst, E, indptr, cursor, csr, N);

    // ---- weight decompose: head-padded N-remap + act-layout K-remap ----
    const int Cc[4] = {125, 75, 50, 30};       // per-head cols
    const int Pc[4] = {128, 76, 52, 32};       // head pad (align 4)
    const int Nc[4] = {250, 150, 100, 60};
    const int Kl[4] = {480, 200, 100, 100};
    const int Nl[4] = {200, 100, 100, 29};
    WtJobs jobs;
    int nb = 0;
    for (int l = 0; l < 4; ++l) {
        WtJob jb;
        jb.W = Wc[l]; jb.Whi = WtHi[l]; jb.Wlo = WtLo[l];
        jb.N = Nc[l]; jb.Kp = KpConv[l]; jb.nb0 = nb;
        jb.Cn = Cc[l]; jb.Pn = Pc[l];
        if (l == 0) { jb.Pk = 0; jb.Ck = 0; jb.kblk = 1; jb.K = 336; }
        else { jb.Pk = Pc[l-1]; jb.Ck = Cc[l-1]; jb.kblk = KpConv[l]; jb.K = 0; }
        jobs.j[l] = jb;
        nb += NpConv[l];
    }
    for (int l = 0; l < 4; ++l) {
        WtJob jb;
        jb.W = LW[l]; jb.Whi = LtHi[l]; jb.Wlo = LtLo[l];
        jb.N = Nl[l]; jb.Kp = KpLin[l]; jb.nb0 = nb;
        jb.Cn = 0; jb.Pn = 0;
        if (l == 0) { jb.Pk = Pc[3]; jb.Ck = Cc[3]; jb.kblk = 64; jb.K = 0; }
        else { jb.Pk = 0; jb.Ck = 0; jb.kblk = 1; jb.K = Kl[l]; }
        jobs.j[4 + l] = jb;
        nb += NpLin[l];
    }
    wt_decomp_all<<<nb, 256, 0, stream>>>(jobs);

    // ---- 4 GAT layers (head-padded fp16 h; stats fused into every gather) ----
    const int HCp[4]  = {256, 152, 104, 64};   // bufC16 stride = 2P
    const int ldoA[4] = {256, 160, 128, 64};   // act stride (= next Kp)
    const int ldaA[4] = {336, 256, 160, 128};  // A leading dim into GEMM
    for (int l = 0; l < 4; ++l) {
        float* alS = alSD + (size_t)l * N * 4;
        float* alD = alS + (size_t)N * 2;
        if (l == 0) {
            gemm_mfma<128><<<dim3(2, N / 128), 256, 0, stream>>>(
                x, 336, nullptr, nullptr, 336, 352,
                WtHi[0], WtLo[0],
                bufC16, HCp[0], HCp[0],
                AS[0], AD[0], alS, alD, Cc[0], Pc[0]);
        } else if (l == 1) {
            gemm_mfma<64><<<dim3(3, N / 128), 256, 0, stream>>>(
                nullptr, 0, actHi, actLo, ldaA[1], KpConv[1],
                WtHi[1], WtLo[1],
                bufC16, HCp[1], HCp[1],
                AS[1], AD[1], alS, alD, Cc[1], Pc[1]);
        } else if (l == 2) {
            gemm_mfma<128><<<dim3(1, N / 128), 256, 0, stream>>>(
                nullptr, 0, actHi, actLo, ldaA[2], KpConv[2],
                WtHi[2], WtLo[2],
                bufC16, HCp[2], HCp[2],
                AS[2], AD[2], alS, alD, Cc[2], Pc[2]);
        } else {
            gemm_mfma<64><<<dim3(1, N / 128), 256, 0, stream>>>(
                nullptr, 0, actHi, actLo, ldaA[3], KpConv[3],
                WtHi[3], WtLo[3],
                bufC16, HCp[3], HCp[3],
                AS[3], AD[3], alS, alD, Cc[3], Pc[3]);
        }
        if (l == 0) {
            gat_gather_fused<64><<<N / 4, 256, 0, stream>>>(
                bufC16, alS, alD, indptr, csr, Bc[0],
                actHi, actLo, ldoA[0], N, Cc[0], Pc[0], HCp[0]);
        } else if (l == 1) {
            gat_gather_fused<64><<<N / 4, 256, 0, stream>>>(
                bufC16, alS, alD, indptr, csr, Bc[1],
                actHi, actLo, ldoA[1], N, Cc[1], Pc[1], HCp[1]);
        } else if (l == 2) {
            gat_gather_fused<32><<<N / 4, 256, 0, stream>>>(
                bufC16, alS, alD, indptr, csr, Bc[2],
                actHi, actLo, ldoA[2], N, Cc[2], Pc[2], HCp[2]);
        } else {
            gat_gather_fused<16><<<N / 4, 256, 0, stream>>>(
                bufC16, alS, alD, indptr, csr, Bc[3],
                actHi, actLo, ldoA[3], N, Cc[3], Pc[3], HCp[3]);
        }
    }

    // ---- MLP head, fused: [8192,480(512 head-padded)] -> 200 -> 100 -> 100 -> 29 ----
    mlp_fused<<<8192 / 32, 256, 0, stream>>>(
        actHi, actLo,
        LtHi[0], LtLo[0], LtHi[1], LtLo[1],
        LtHi[2], LtLo[2], LtHi[3], LtLo[3],
        LB[0], LB[1], LB[2], LB[3],
        (float*)d_out);
}